// Round 14
// baseline (706.270 us; speedup 1.0000x reference)
//
#include <hip/hip_runtime.h>

// ============================================================================
// New_LinkNet GNN forward — MFMA bf16 GEMMs + fused gate updates.
// Round-14 changes vs round 13 (698us; attn at gather-BW ceiling ~3.5TB/s;
// gemm_p reads aob twice on different XCDs; classifier 2 launches):
//  - gemm_p: 1D bijective XCD-chunked grid pairing (bm,node)+(bm,edge) in the
//    same XCD chunk -> aob tile re-read hits that XCD's L2 (~25MB/iter).
//  - classifier: single gemm_gate<0> launch, blockIdx.y selects Wc1 half.
// ============================================================================

#define LN_EPS 1e-5f
#define PBLK 512

typedef __attribute__((ext_vector_type(8))) short bf16x8;
typedef __attribute__((ext_vector_type(4))) float f32x4;

static __device__ __forceinline__ float wsum(float v) {
#pragma unroll
  for (int d = 32; d > 0; d >>= 1) v += __shfl_xor(v, d);
  return v;
}
static __device__ __forceinline__ float sigm(float x) { return 1.0f / (1.0f + __expf(-x)); }
static __device__ __forceinline__ unsigned short f2bf(float f) {
  unsigned int u = __float_as_uint(f);
  u += 0x7FFFu + ((u >> 16) & 1u);
  return (unsigned short)(u >> 16);
}
static __device__ __forceinline__ float bf2f(unsigned short b) {
  return __uint_as_float(((unsigned int)b) << 16);
}
static __device__ __forceinline__ float4 ld4v(const float* p) { return *(const float4*)p; }
static __device__ __forceinline__ float4 ld4v(const unsigned short* p) {
  union { uint2 u; unsigned short h[4]; } t;
  t.u = *(const uint2*)p;
  return make_float4(bf2f(t.h[0]), bf2f(t.h[1]), bf2f(t.h[2]), bf2f(t.h[3]));
}
static __device__ __forceinline__ void st4v(float* p, float4 v) { *(float4*)p = v; }
static __device__ __forceinline__ void st4v(unsigned short* p, float4 v) {
  union { uint2 u; unsigned short h[4]; } t;
  t.h[0] = f2bf(v.x); t.h[1] = f2bf(v.y); t.h[2] = f2bf(v.z); t.h[3] = f2bf(v.w);
  *(uint2*)p = t.u;
}

// ---------------- util ----------------
__global__ __launch_bounds__(256) void k_zero2(int* __restrict__ a, int* __restrict__ b, int n) {
  int i = blockIdx.x * 256 + threadIdx.x;
  if (i < n) { a[i] = 0; b[i] = 0; }
}

__global__ __launch_bounds__(256) void k_sentinel(float* __restrict__ out, int n) {
  int i = blockIdx.x * 256 + threadIdx.x;
  if (i < n) out[i] = 1.0e6f;
}

// ---------------- CSR build (by dst) ----------------
__global__ __launch_bounds__(256) void k_hist(const int* __restrict__ ei, int* __restrict__ cnt, int E) {
  int e = blockIdx.x * 256 + threadIdx.x;
  if (e >= 2 * E) return;
  int d = (e < E) ? ei[E + e] : ei[e - E];
  atomicAdd(&cnt[d], 1);
}

__global__ __launch_bounds__(256) void k_scan1(const int* __restrict__ cnt, int* __restrict__ off,
                                               int* __restrict__ bsum, int n) {
  const int t = threadIdx.x;
  const int lane = t & 63, w = t >> 6;
  const int i0 = blockIdx.x * 1024 + t * 4;
  int v0 = (i0 + 0 < n) ? cnt[i0 + 0] : 0;
  int v1 = (i0 + 1 < n) ? cnt[i0 + 1] : 0;
  int v2 = (i0 + 2 < n) ? cnt[i0 + 2] : 0;
  int v3 = (i0 + 3 < n) ? cnt[i0 + 3] : 0;
  int s = v0 + v1 + v2 + v3;
  int sc = s;
#pragma unroll
  for (int d = 1; d < 64; d <<= 1) {
    int tv = __shfl_up(sc, d);
    if (lane >= d) sc += tv;
  }
  __shared__ int wsums[4];
  if (lane == 63) wsums[w] = sc;
  __syncthreads();
  int wbase = 0;
#pragma unroll
  for (int k = 0; k < 4; ++k)
    if (k < w) wbase += wsums[k];
  int run = wbase + sc - s;
  if (i0 + 0 < n) off[i0 + 0] = run; run += v0;
  if (i0 + 1 < n) off[i0 + 1] = run; run += v1;
  if (i0 + 2 < n) off[i0 + 2] = run; run += v2;
  if (i0 + 3 < n) off[i0 + 3] = run;
  if (t == 255) bsum[blockIdx.x] = wbase + sc;
}

__global__ __launch_bounds__(64) void k_scan2(const int* __restrict__ bsum, int* __restrict__ boff,
                                              int* __restrict__ off, int n, int nblk) {
  const int lane = threadIdx.x;
  int carry = 0;
  for (int base = 0; base < nblk; base += 64) {
    int i = base + lane;
    int v = (i < nblk) ? bsum[i] : 0;
    int sc = v;
#pragma unroll
    for (int d = 1; d < 64; d <<= 1) {
      int tv = __shfl_up(sc, d);
      if (lane >= d) sc += tv;
    }
    if (i < nblk) boff[i] = carry + sc - v;
    carry += __shfl(sc, 63);
  }
  if (lane == 0) off[n] = carry;
}

__global__ __launch_bounds__(256) void k_scan3(int* __restrict__ off, const int* __restrict__ boff, int n) {
  int i = blockIdx.x * 256 + threadIdx.x;
  if (i < n) off[i] += boff[i >> 10];
}

__global__ __launch_bounds__(256) void k_scatter(const int* __restrict__ ei, const int* __restrict__ off,
                                                 int* __restrict__ cur, int* __restrict__ pinv,
                                                 int* __restrict__ slist, int E) {
  int e = blockIdx.x * 256 + threadIdx.x;
  if (e >= 2 * E) return;
  int d = (e < E) ? ei[E + e] : ei[e - E];
  int pos = atomicAdd(&cur[d], 1);
  int base = off[d] + pos;
  pinv[e] = base;
  slist[base] = ei[e];
}

// ---------------- pack all transposed bf16 weights ----------------
// B2 col order: [npj | vn | pe | ve]
__global__ __launch_bounds__(256) void k_packW(
    const float* __restrict__ Wq, const float* __restrict__ Wk, const float* __restrict__ Wv,
    const float* __restrict__ Ws, const float* __restrict__ bq, const float* __restrict__ bk,
    const float* __restrict__ bv, const float* __restrict__ bs,
    const float* __restrict__ Wpn, const float* __restrict__ Wpe,
    const float* __restrict__ bpn, const float* __restrict__ bpe,
    const float* __restrict__ Wg, const float* __restrict__ Wc1,
    unsigned short* __restrict__ W1t, float* __restrict__ bias1,
    unsigned short* __restrict__ B2t, float* __restrict__ bias2,
    unsigned short* __restrict__ Wg1t, unsigned short* __restrict__ Wc1t) {
  const int S1 = 3 * 1024 * 128, S2 = 3 * 1024, S3 = 3 * 256 * 256, S4 = 3 * 256;
  const int S5 = 3 * 64 * 64, S6 = 2 * 64 * 64;
  int idx = blockIdx.x * 256 + threadIdx.x;
  if (idx < S1) {
    int i = idx / 131072, r = idx % 131072;
    int col = r >> 7, k = r & 127;
    int m = col >> 8, cc = col & 255;
    const float* W = (m == 0) ? Wq : (m == 1) ? Wk : (m == 2) ? Wv : Ws;
    W1t[idx] = f2bf(W[i * 32768 + k * 256 + cc]);
  } else if (idx < S1 + S2) {
    int j = idx - S1;
    int i = j >> 10, col = j & 1023;
    int m = col >> 8, cc = col & 255;
    const float* bsrc = (m == 0) ? bq : (m == 1) ? bk : (m == 2) ? bv : bs;
    bias1[j] = bsrc[i * 256 + cc];
  } else if (idx < S1 + S2 + S3) {
    int j = idx - S1 - S2;
    int i = j / 65536, r = j % 65536;
    int col = r >> 8, k = r & 255;
    int half = col >> 6, cc = col & 63;
    float v;
    if (half == 0) v = Wpn[i * 16384 + k * 64 + cc];
    else if (half == 2) v = Wpe[i * 16384 + k * 64 + cc];
    else {
      const float* Wsrc = (half == 1) ? Wpn : Wpe;
      float acc = 0.f;
      for (int jj = 0; jj < 64; ++jj)
        acc = fmaf(Wsrc[i * 16384 + k * 64 + jj], Wg[i * 8192 + (64 + jj) * 64 + cc], acc);
      v = acc;
    }
    B2t[j] = f2bf(v);
  } else if (idx < S1 + S2 + S3 + S4) {
    int j = idx - S1 - S2 - S3;
    int i = j >> 8, col = j & 255;
    int half = col >> 6, cc = col & 63;
    float v;
    if (half == 0) v = bpn[i * 64 + cc];
    else if (half == 2) v = bpe[i * 64 + cc];
    else {
      const float* bsrc = (half == 1) ? bpn : bpe;
      float acc = 0.f;
      for (int jj = 0; jj < 64; ++jj)
        acc = fmaf(bsrc[i * 64 + jj], Wg[i * 8192 + (64 + jj) * 64 + cc], acc);
      v = acc;
    }
    bias2[j] = v;
  } else if (idx < S1 + S2 + S3 + S4 + S5) {
    int j = idx - S1 - S2 - S3 - S4;
    int i = j / 4096, r = j % 4096;
    int col = r >> 6, k = r & 63;
    Wg1t[j] = f2bf(Wg[i * 8192 + k * 64 + col]);
  } else if (idx < S1 + S2 + S3 + S4 + S5 + S6) {
    int j = idx - S1 - S2 - S3 - S4 - S5;
    int h = j / 4096, r = j % 4096;
    int col = r >> 6, k = r & 63;
    Wc1t[j] = f2bf(Wc1[(h * 64 + k) * 64 + col]);
  }
}

// ---------------- embeddings ----------------
__global__ __launch_bounds__(256) void k_node_embed(
    const float* __restrict__ x, const int* __restrict__ zk, const float* __restrict__ zt,
    const float* __restrict__ Wn, const float* __restrict__ bn, float* __restrict__ nf, int N) {
  int n = blockIdx.x * 4 + (threadIdx.x >> 6);
  int lane = threadIdx.x & 63;
  if (n >= N) return;
  const float* xr = x + (size_t)n * 6;
  float acc = bn[lane];
#pragma unroll
  for (int d = 0; d < 6; ++d) acc = fmaf(xr[d], Wn[d * 64 + lane], acc);
  int zi = __float2int_rn(xr[2]);
  int idx = 0;
#pragma unroll
  for (int t = 5; t >= 0; --t)
    if (zi == zk[t]) idx = t;
  nf[(size_t)n * 64 + lane] = fmaxf(acc, 0.0f) + zt[idx * 64 + lane];
}

__global__ __launch_bounds__(256) void k_edge_embed(
    const float* __restrict__ x, const float* __restrict__ ea, const int* __restrict__ ei,
    const float* __restrict__ We, const float* __restrict__ be,
    unsigned short* __restrict__ ef, int E) {
  int e = blockIdx.x * 4 + (threadIdx.x >> 6);
  int lane = threadIdx.x & 63;
  if (e >= 2 * E) return;
  int e0 = (e < E) ? e : e - E;
  int s = ei[e];
  int d = (e < E) ? ei[E + e] : ei[e - E];
  const float* ar = ea + (size_t)e0 * 4;
  const float* xs = x + (size_t)s * 6;
  const float* xd = x + (size_t)d * 6;
  float in[7];
  in[0] = ar[0]; in[1] = ar[1]; in[2] = ar[2]; in[3] = ar[3];
  in[4] = xs[0] - xd[0]; in[5] = xs[1] - xd[1]; in[6] = xs[2] - xd[2];
  float acc = be[lane];
#pragma unroll
  for (int dd = 0; dd < 7; ++dd) acc = fmaf(in[dd], We[dd * 64 + lane], acc);
  ef[(size_t)e * 64 + lane] = f2bf(fmaxf(acc, 0.0f));
}

// ---------------- CBAM (vectorized, fp32 or bf16 buffer) ----------------
template <typename T>
__global__ __launch_bounds__(256) void k_pool_partial(const T* __restrict__ buf, int n,
                                                      float* __restrict__ pm, float* __restrict__ ps) {
  const int w = threadIdx.x >> 6, l = threadIdx.x & 63;
  const int rsub = l >> 4, c4 = (l & 15) << 2;
  float4 mx = make_float4(-INFINITY, -INFINITY, -INFINITY, -INFINITY);
  float4 sm = make_float4(0.f, 0.f, 0.f, 0.f);
  for (int r = blockIdx.x * 16 + w * 4 + rsub; r < n; r += gridDim.x * 16) {
    float4 v = ld4v(buf + (size_t)r * 64 + c4);
    mx.x = fmaxf(mx.x, v.x); mx.y = fmaxf(mx.y, v.y);
    mx.z = fmaxf(mx.z, v.z); mx.w = fmaxf(mx.w, v.w);
    sm.x += v.x; sm.y += v.y; sm.z += v.z; sm.w += v.w;
  }
#pragma unroll
  for (int d = 16; d < 64; d <<= 1) {
    mx.x = fmaxf(mx.x, __shfl_xor(mx.x, d)); mx.y = fmaxf(mx.y, __shfl_xor(mx.y, d));
    mx.z = fmaxf(mx.z, __shfl_xor(mx.z, d)); mx.w = fmaxf(mx.w, __shfl_xor(mx.w, d));
    sm.x += __shfl_xor(sm.x, d); sm.y += __shfl_xor(sm.y, d);
    sm.z += __shfl_xor(sm.z, d); sm.w += __shfl_xor(sm.w, d);
  }
  __shared__ float smx[4][64], ssm[4][64];
  if (l < 16) {
    *(float4*)&smx[w][c4] = mx;
    *(float4*)&ssm[w][c4] = sm;
  }
  __syncthreads();
  if (threadIdx.x < 64) {
    int t = threadIdx.x;
    float m2 = fmaxf(fmaxf(smx[0][t], smx[1][t]), fmaxf(smx[2][t], smx[3][t]));
    float s2 = ssm[0][t] + ssm[1][t] + ssm[2][t] + ssm[3][t];
    pm[blockIdx.x * 64 + t] = m2;
    ps[blockIdx.x * 64 + t] = s2;
  }
}

__global__ __launch_bounds__(256) void k_pool_final(
    const float* __restrict__ pm, const float* __restrict__ ps, int n, int nblk,
    const float* __restrict__ w1, const float* __restrict__ b1,
    const float* __restrict__ w2, const float* __restrict__ b2, float* __restrict__ cw) {
  __shared__ float redm[4][64], reds[4][64];
  __shared__ float cat[128];
  __shared__ float hid[4];
  int t = threadIdx.x;
  int g = t >> 6, col = t & 63;
  float mx = -INFINITY, sm = 0.0f;
  for (int p = g; p < nblk; p += 4) {
    mx = fmaxf(mx, pm[p * 64 + col]);
    sm += ps[p * 64 + col];
  }
  redm[g][col] = mx;
  reds[g][col] = sm;
  __syncthreads();
  if (t < 64) {
    float m2 = fmaxf(fmaxf(redm[0][t], redm[1][t]), fmaxf(redm[2][t], redm[3][t]));
    float s2 = reds[0][t] + reds[1][t] + reds[2][t] + reds[3][t];
    cat[t] = m2;
    cat[64 + t] = s2 / (float)n;
  }
  __syncthreads();
  if (t < 4) {
    float a = b1[t];
    for (int k = 0; k < 128; ++k) a = fmaf(cat[k], w1[k * 4 + t], a);
    hid[t] = fmaxf(a, 0.0f);
  }
  __syncthreads();
  if (t < 64) {
    float a = b2[t];
#pragma unroll
    for (int h = 0; h < 4; ++h) a = fmaf(hid[h], w2[h * 64 + t], a);
    cw[t] = sigm(a);
  }
}

template <typename T>
__global__ __launch_bounds__(256) void k_chan_sp(T* __restrict__ buf, int n,
                                                 const float* __restrict__ cw,
                                                 float* __restrict__ spmax, float* __restrict__ spmean) {
  const int w = threadIdx.x >> 6, l = threadIdx.x & 63;
  const int rsub = l >> 4, c4 = (l & 15) << 2;
  int r = blockIdx.x * 16 + w * 4 + rsub;
  if (r >= n) return;
  float4 cwv = *(const float4*)(cw + c4);
  float4 v = ld4v(buf + (size_t)r * 64 + c4);
  v.x *= cwv.x; v.y *= cwv.y; v.z *= cwv.z; v.w *= cwv.w;
  st4v(buf + (size_t)r * 64 + c4, v);
  float mx = fmaxf(fmaxf(v.x, v.y), fmaxf(v.z, v.w));
  float sm = v.x + v.y + v.z + v.w;
#pragma unroll
  for (int d = 1; d < 16; d <<= 1) {
    mx = fmaxf(mx, __shfl_xor(mx, d));
    sm += __shfl_xor(sm, d);
  }
  if ((l & 15) == 0) {
    spmax[r] = mx;
    spmean[r] = sm * (1.0f / 64.0f);
  }
}

__global__ __launch_bounds__(256) void k_conv(const float* __restrict__ spmax, const float* __restrict__ spmean,
                                              int n, const float* __restrict__ w1, const float* __restrict__ b1,
                                              const float* __restrict__ w2, const float* __restrict__ b2,
                                              float* __restrict__ s) {
  __shared__ float tl[258];
  int base = blockIdx.x * 256;
  for (int q = threadIdx.x; q < 258; q += 256) {
    int p = base - 1 + q;
    float t = 0.0f;
    if (p >= 0 && p < n) {
      float a = b1[0];
#pragma unroll
      for (int h = 0; h < 5; ++h) {
        int pp = p + h - 2;
        if (pp >= 0 && pp < n) a += spmax[pp] * w1[h] + spmean[pp] * w1[5 + h];
      }
      t = fmaxf(a, 0.0f);
    }
    tl[q] = t;
  }
  __syncthreads();
  int o = base + threadIdx.x;
  if (o < n) {
    float a = b2[0] + tl[threadIdx.x] * w2[0] + tl[threadIdx.x + 1] * w2[1] + tl[threadIdx.x + 2] * w2[2];
    s[o] = sigm(a);
  }
}

__global__ __launch_bounds__(256) void k_row_scale(float* __restrict__ buf, int n, const float* __restrict__ s) {
  int i4 = blockIdx.x * 256 + threadIdx.x;
  if (i4 >= n * 16) return;
  int r = i4 >> 4;
  float sc = s[r];
  float4 v = ld4v(buf + (size_t)i4 * 4);
  v.x *= sc; v.y *= sc; v.z *= sc; v.w *= sc;
  st4v(buf + (size_t)i4 * 4, v);
}

__global__ __launch_bounds__(256) void k_row_scale_perm(const unsigned short* __restrict__ src, int n,
                                                        const float* __restrict__ s,
                                                        const int* __restrict__ pinv,
                                                        unsigned short* __restrict__ dst) {
  int i4 = blockIdx.x * 256 + threadIdx.x;
  if (i4 >= n * 16) return;
  int r = i4 >> 4, c4 = (i4 & 15) * 4;
  float sc = s[r];
  float4 v = ld4v(src + (size_t)r * 64 + c4);
  v.x *= sc; v.y *= sc; v.z *= sc; v.w *= sc;
  st4v(dst + (size_t)pinv[r] * 64 + c4, v);
}

// ---------------- agg + concat-LN (CSR-ordered bf16 ef, streaming) --------
__global__ __launch_bounds__(256) void k_aggcomb(const unsigned short* __restrict__ efc,
                                                 const float* __restrict__ nf,
                                                 const int* __restrict__ off,
                                                 unsigned short* __restrict__ comb, const float* __restrict__ g,
                                                 const float* __restrict__ b, int N) {
  int n = blockIdx.x * 4 + (threadIdx.x >> 6);
  int lane = threadIdx.x & 63;
  if (n >= N) return;
  float agg = 0.0f;
  int i0 = off[n], i1 = off[n + 1];
  for (int idx = i0; idx < i1; ++idx) agg += bf2f(efc[(size_t)idx * 64 + lane]);
  float y0 = nf[(size_t)n * 64 + lane];
  float y1 = agg - y0;
  float s1 = wsum(y0 + y1);
  float s2 = wsum(y0 * y0 + y1 * y1);
  float mu = s1 * (1.0f / 128.0f);
  float var = s2 * (1.0f / 128.0f) - mu * mu;
  float rs = rsqrtf(fmaxf(var, 0.0f) + LN_EPS);
  comb[(size_t)n * 128 + lane] = f2bf((y0 - mu) * rs * g[lane] + b[lane]);
  comb[(size_t)n * 128 + 64 + lane] = f2bf((y1 - mu) * rs * g[64 + lane] + b[64 + lane]);
}

// ---------------- MFMA GEMM: QKVS (XCD-swizzled) --------------------------
__global__ __launch_bounds__(256) void gemm_mfma(
    const unsigned short* __restrict__ A, int M, int K,
    const unsigned short* __restrict__ Bt, const float* __restrict__ bias,
    unsigned short* __restrict__ outQ, unsigned short* __restrict__ outK,
    unsigned short* __restrict__ outS) {
  __shared__ unsigned short shmem[128 * 136];
  unsigned short* As = shmem;
  unsigned short* Bs = shmem + 128 * 64;
  const int tid = threadIdx.x;
  int cpx = gridDim.x >> 3;
  int wgid = (blockIdx.x & 7) * cpx + (blockIdx.x >> 3);
  int bm = (wgid >> 3) * 128;
  int bn = (wgid & 7) * 128;
  const int wid = tid >> 6, lane = tid & 63;
  const int wr = (wid >> 1) * 64, wc = (wid & 1) * 64;
  const int lrow = lane & 15, lkb = (lane >> 4) * 8;
  f32x4 acc[4][4];
#pragma unroll
  for (int m = 0; m < 4; ++m)
#pragma unroll
    for (int n = 0; n < 4; ++n) acc[m][n] = (f32x4){0.f, 0.f, 0.f, 0.f};

  for (int k0 = 0; k0 < K; k0 += 64) {
#pragma unroll
    for (int l = 0; l < 4; ++l) {
      int c = tid + l * 256;
      int row = c >> 3, kc = (c & 7) * 8;
      int sw = row * 64 + (kc ^ ((row & 7) << 3));
      int grow = bm + row;
      bf16x8 v = {0, 0, 0, 0, 0, 0, 0, 0};
      if (grow < M) v = *(const bf16x8*)(A + (size_t)grow * K + k0 + kc);
      *(bf16x8*)&As[sw] = v;
      int gcol = bn + row;
      *(bf16x8*)&Bs[sw] = *(const bf16x8*)(Bt + (size_t)gcol * K + k0 + kc);
    }
    __syncthreads();
#pragma unroll
    for (int ks = 0; ks < 2; ++ks) {
      const int ke = ks * 32 + lkb;
      bf16x8 af[4], bfr[4];
#pragma unroll
      for (int m = 0; m < 4; ++m) {
        int row = wr + m * 16 + lrow;
        af[m] = *(const bf16x8*)&As[row * 64 + (ke ^ ((row & 7) << 3))];
      }
#pragma unroll
      for (int n = 0; n < 4; ++n) {
        int col = wc + n * 16 + lrow;
        bfr[n] = *(const bf16x8*)&Bs[col * 64 + (ke ^ ((col & 7) << 3))];
      }
#pragma unroll
      for (int m = 0; m < 4; ++m)
#pragma unroll
        for (int n = 0; n < 4; ++n)
          acc[m][n] = __builtin_amdgcn_mfma_f32_16x16x32_bf16(af[m], bfr[n], acc[m][n], 0, 0, 0);
    }
    __syncthreads();
  }

  const int colw = lane & 15, rq = (lane >> 4) * 4;
  unsigned short* Cs = shmem;
#pragma unroll
  for (int m = 0; m < 4; ++m) {
#pragma unroll
    for (int n = 0; n < 4; ++n) {
      int col = wc + n * 16 + colw;
      float bv = bias[bn + col];
#pragma unroll
      for (int r = 0; r < 4; ++r) {
        int row = wr + m * 16 + rq + r;
        Cs[row * 136 + col] = f2bf(acc[m][n][r] + bv);
      }
    }
  }
  __syncthreads();
  const int rsub = tid >> 4, c8 = (tid & 15) * 8;
#pragma unroll
  for (int i = 0; i < 8; ++i) {
    int row = i * 16 + rsub;
    int grow = bm + row;
    if (grow >= M) continue;
    uint4 v = *(const uint4*)&Cs[row * 136 + c8];
    const int proj = bn >> 8;
    int cc = (bn & 255) + c8;
    if (proj == 0) *(uint4*)(outQ + (size_t)grow * 256 + cc) = v;
    else if (proj == 1) *(uint4*)(outK + (size_t)grow * 512 + cc) = v;
    else if (proj == 2) *(uint4*)(outK + (size_t)grow * 512 + 256 + cc) = v;
    else *(uint4*)(outS + (size_t)grow * 256 + cc) = v;
  }
}

// ---------- fused P GEMM: paired 1D grid (bijective XCD chunking) ----------
// even wgid: node path (P-node + Sn + gate update); odd wgid: edge (Pe).
__global__ __launch_bounds__(256) void gemm_p(
    const unsigned short* __restrict__ aob, float* __restrict__ nf, int N,
    const unsigned short* __restrict__ B2t, const float* __restrict__ bias2,
    const unsigned short* __restrict__ Wg1t, const float* __restrict__ bgv,
    unsigned short* __restrict__ Pe) {
  __shared__ unsigned short shmem[128 * 136];
  unsigned short* As = shmem;
  unsigned short* Bs = shmem + 128 * 64;
  const int tid = threadIdx.x;
  // bijective chunked XCD swizzle (nwg % 8 may be != 0)
  const int nwg = gridDim.x;
  const int q = nwg >> 3, rres = nwg & 7;
  const int xcd = blockIdx.x & 7, ii = blockIdx.x >> 3;
  const int wgid = ((xcd < rres) ? xcd * (q + 1) : rres * (q + 1) + (xcd - rres) * q) + ii;
  const int bm = (wgid >> 1) * 128;
  const bool nodeblk = (wgid & 1) == 0;
  const int wid = tid >> 6, lane = tid & 63;
  const int lrow = lane & 15, lkb = (lane >> 4) * 8;

  f32x4 accS[2][4];
  if (nodeblk) {
#pragma unroll
    for (int l = 0; l < 8; ++l) {
      int u = tid + l * 256;
      int row = u >> 4, k4 = (u & 15) << 2;
      int grow = bm + row;
      float4 v = make_float4(0.f, 0.f, 0.f, 0.f);
      if (grow < N) v = *(const float4*)(nf + (size_t)grow * 64 + k4);
      union { unsigned short h[4]; uint2 q2; } pk;
      pk.h[0] = f2bf(v.x); pk.h[1] = f2bf(v.y); pk.h[2] = f2bf(v.z); pk.h[3] = f2bf(v.w);
      *(uint2*)&As[row * 64 + (k4 ^ ((row & 7) << 3))] = pk.q2;
    }
#pragma unroll
    for (int l = 0; l < 2; ++l) {
      int u = tid + l * 256;
      int row = u >> 3, kc = (u & 7) * 8;
      *(bf16x8*)&Bs[row * 64 + (kc ^ ((row & 7) << 3))] = *(const bf16x8*)(Wg1t + row * 64 + kc);
    }
    __syncthreads();
    const int wrS = wid * 32;
#pragma unroll
    for (int m = 0; m < 2; ++m)
#pragma unroll
      for (int n = 0; n < 4; ++n) accS[m][n] = (f32x4){0.f, 0.f, 0.f, 0.f};
#pragma unroll
    for (int ks = 0; ks < 2; ++ks) {
      const int ke = ks * 32 + lkb;
      bf16x8 af[2], wf[4];
#pragma unroll
      for (int m = 0; m < 2; ++m) {
        int row = wrS + m * 16 + lrow;
        af[m] = *(const bf16x8*)&As[row * 64 + (ke ^ ((row & 7) << 3))];
      }
#pragma unroll
      for (int n = 0; n < 4; ++n) {
        int col = n * 16 + lrow;
        wf[n] = *(const bf16x8*)&Bs[col * 64 + (ke ^ ((col & 7) << 3))];
      }
#pragma unroll
      for (int m = 0; m < 2; ++m)
#pragma unroll
        for (int n = 0; n < 4; ++n)
          accS[m][n] = __builtin_amdgcn_mfma_f32_16x16x32_bf16(af[m], wf[n], accS[m][n], 0, 0, 0);
    }
    __syncthreads();
  }

  const int cbase = nodeblk ? 0 : 128;
  const int wr = (wid >> 1) * 64, wc = (wid & 1) * 64;
  f32x4 acc[4][4];
#pragma unroll
  for (int m = 0; m < 4; ++m)
#pragma unroll
    for (int n = 0; n < 4; ++n) acc[m][n] = (f32x4){0.f, 0.f, 0.f, 0.f};
  for (int k0 = 0; k0 < 256; k0 += 64) {
#pragma unroll
    for (int l = 0; l < 4; ++l) {
      int c = tid + l * 256;
      int row = c >> 3, kc = (c & 7) * 8;
      int sw = row * 64 + (kc ^ ((row & 7) << 3));
      int grow = bm + row;
      bf16x8 v = {0, 0, 0, 0, 0, 0, 0, 0};
      if (grow < N) v = *(const bf16x8*)(aob + (size_t)grow * 256 + k0 + kc);
      *(bf16x8*)&As[sw] = v;
      *(bf16x8*)&Bs[sw] = *(const bf16x8*)(B2t + (size_t)(cbase + row) * 256 + k0 + kc);
    }
    __syncthreads();
#pragma unroll
    for (int ks = 0; ks < 2; ++ks) {
      const int ke = ks * 32 + lkb;
      bf16x8 af[4], bfr[4];
#pragma unroll
      for (int m = 0; m < 4; ++m) {
        int row = wr + m * 16 + lrow;
        af[m] = *(const bf16x8*)&As[row * 64 + (ke ^ ((row & 7) << 3))];
      }
#pragma unroll
      for (int n = 0; n < 4; ++n) {
        int col = wc + n * 16 + lrow;
        bfr[n] = *(const bf16x8*)&Bs[col * 64 + (ke ^ ((col & 7) << 3))];
      }
#pragma unroll
      for (int m = 0; m < 4; ++m)
#pragma unroll
        for (int n = 0; n < 4; ++n)
          acc[m][n] = __builtin_amdgcn_mfma_f32_16x16x32_bf16(af[m], bfr[n], acc[m][n], 0, 0, 0);
    }
    __syncthreads();
  }

  const int colw = lane & 15, rq = (lane >> 4) * 4;
  unsigned short* Cs = shmem;
#pragma unroll
  for (int m = 0; m < 4; ++m) {
#pragma unroll
    for (int n = 0; n < 4; ++n) {
      int col = wc + n * 16 + colw;
      float bv = bias2[cbase + col];
#pragma unroll
      for (int r = 0; r < 4; ++r) {
        int row = wr + m * 16 + rq + r;
        Cs[row * 136 + col] = f2bf(acc[m][n][r] + bv);
      }
    }
  }
  __syncthreads();

  if (nodeblk) {
    const int wrS = wid * 32;
#pragma unroll
    for (int m = 0; m < 2; ++m) {
#pragma unroll
      for (int r = 0; r < 4; ++r) {
        int row = wrS + m * 16 + rq + r;
        int grow = bm + row;
        if (grow >= N) continue;
#pragma unroll
        for (int n = 0; n < 4; ++n) {
          int c = n * 16 + colw;
          float g = sigm(accS[m][n][r] + bf2f(Cs[row * 136 + 64 + c]) + bgv[c]);
          size_t oi = (size_t)grow * 64 + c;
          float old = nf[oi];
          nf[oi] = old * g + bf2f(Cs[row * 136 + c]) * (1.0f - g);
        }
      }
    }
  } else {
    const int rsub = tid >> 4, c8 = (tid & 15) * 8;
#pragma unroll
    for (int i = 0; i < 8; ++i) {
      int row = i * 16 + rsub;
      int grow = bm + row;
      if (grow >= N) continue;
      *(uint4*)(Pe + (size_t)grow * 128 + c8) = *(const uint4*)&Cs[row * 136 + c8];
    }
  }
}

// ------ MFMA [M,64]@[64,64] with fused epilogue ------
// UPD 0: fp32 A, fp32 C; blockIdx.y selects Wt half + output half (classifier).
// UPD 2: bf16 A (efc), bf16 edge-gate update with Pe[N,128]; src from srcl.
template <int UPD>
__global__ __launch_bounds__(256) void gemm_gate(
    const void* __restrict__ Av, int M, const unsigned short* __restrict__ Wt,
    const unsigned short* __restrict__ P, const float* __restrict__ bgv,
    const int* __restrict__ srcl, void* __restrict__ updv) {
  __shared__ unsigned short As[128 * 64];
  __shared__ unsigned short Ws[64 * 64];
  const int tid = threadIdx.x;
  const int bm = blockIdx.x * 128;
  if (UPD == 0) Wt += (size_t)blockIdx.y * 4096;
  if (UPD == 2) {
    const unsigned short* Ab = (const unsigned short*)Av;
#pragma unroll
    for (int l = 0; l < 4; ++l) {
      int u = tid + l * 256;
      int row = u >> 3, kc = (u & 7) * 8;
      int grow = bm + row;
      bf16x8 v = {0, 0, 0, 0, 0, 0, 0, 0};
      if (grow < M) v = *(const bf16x8*)(Ab + (size_t)grow * 64 + kc);
      *(bf16x8*)&As[row * 64 + (kc ^ ((row & 7) << 3))] = v;
    }
  } else {
    const float* Af = (const float*)Av;
#pragma unroll
    for (int l = 0; l < 8; ++l) {
      int u = tid + l * 256;
      int row = u >> 4, k4 = (u & 15) << 2;
      int grow = bm + row;
      float4 v = make_float4(0.f, 0.f, 0.f, 0.f);
      if (grow < M) v = *(const float4*)(Af + (size_t)grow * 64 + k4);
      union { unsigned short h[4]; uint2 q; } pk;
      pk.h[0] = f2bf(v.x); pk.h[1] = f2bf(v.y); pk.h[2] = f2bf(v.z); pk.h[3] = f2bf(v.w);
      *(uint2*)&As[row * 64 + (k4 ^ ((row & 7) << 3))] = pk.q;
    }
  }
#pragma unroll
  for (int l = 0; l < 2; ++l) {
    int u = tid + l * 256;
    int row = u >> 3, kc = (u & 7) * 8;
    *(bf16x8*)&Ws[row * 64 + (kc ^ ((row & 7) << 3))] = *(const bf16x8*)(Wt + row * 64 + kc);
  }
  __syncthreads();
  const int wid = tid >> 6, lane = tid & 63;
  const int wr = wid * 32;
  const int lrow = lane & 15, lkb = (lane >> 4) * 8;
  f32x4 acc[2][4];
#pragma unroll
  for (int m = 0; m < 2; ++m)
#pragma unroll
    for (int n = 0; n < 4; ++n) acc[m][n] = (f32x4){0.f, 0.f, 0.f, 0.f};
#pragma unroll
  for (int ks = 0; ks < 2; ++ks) {
    const int ke = ks * 32 + lkb;
    bf16x8 af[2], wf[4];
#pragma unroll
    for (int m = 0; m < 2; ++m) {
      int row = wr + m * 16 + lrow;
      af[m] = *(const bf16x8*)&As[row * 64 + (ke ^ ((row & 7) << 3))];
    }
#pragma unroll
    for (int n = 0; n < 4; ++n) {
      int col = n * 16 + lrow;
      wf[n] = *(const bf16x8*)&Ws[col * 64 + (ke ^ ((col & 7) << 3))];
    }
#pragma unroll
    for (int m = 0; m < 2; ++m)
#pragma unroll
      for (int n = 0; n < 4; ++n)
        acc[m][n] = __builtin_amdgcn_mfma_f32_16x16x32_bf16(af[m], wf[n], acc[m][n], 0, 0, 0);
  }
  const int colw = lane & 15, rq = (lane >> 4) * 4;
#pragma unroll
  for (int m = 0; m < 2; ++m) {
#pragma unroll
    for (int r = 0; r < 4; ++r) {
      int e = bm + wr + m * 16 + rq + r;
      if (e >= M) continue;
      if (UPD == 0) {
        float* upd = (float*)updv + (size_t)blockIdx.y * M * 64;
#pragma unroll
        for (int n = 0; n < 4; ++n) upd[(size_t)e * 64 + n * 16 + colw] = acc[m][n][r];
      } else {
        unsigned short* upd = (unsigned short*)updv;
        int s = srcl[e];
        const unsigned short* Pr = P + (size_t)s * 128;
#pragma unroll
        for (int n = 0; n < 4; ++n) {
          int c = n * 16 + colw;
          float g = sigm(acc[m][n][r] + bf2f(Pr[64 + c]) + bgv[c]);
          size_t oi = (size_t)e * 64 + c;
          float vA = bf2f(upd[oi]);
          upd[oi] = f2bf(vA * g + bf2f(Pr[c]) * (1.0f - g));
        }
      }
    }
  }
}

// ---------------- attention: no-max softmax, 4-edge unrolled --------------
__global__ __launch_bounds__(256) void k_attn(const unsigned short* __restrict__ qo,
                                              const unsigned short* __restrict__ kv,
                                              const unsigned short* __restrict__ skipb, const int* __restrict__ off,
                                              const int* __restrict__ slist,
                                              unsigned short* __restrict__ aob,
                                              const float* __restrict__ g, const float* __restrict__ b, int N) {
  int n = blockIdx.x * 4 + (threadIdx.x >> 6);
  int lane = threadIdx.x & 63;
  if (n >= N) return;
  union { uint2 u; unsigned short h[4]; } qq;
  qq.u = *(const uint2*)(qo + (size_t)n * 256 + 4 * lane);
  float q0 = bf2f(qq.h[0]), q1 = bf2f(qq.h[1]), q2 = bf2f(qq.h[2]), q3 = bf2f(qq.h[3]);
  float lsum = 0.f;
  float a0 = 0.f, a1 = 0.f, a2 = 0.f, a3 = 0.f;
  int i0 = off[n], i1 = off[n + 1];
  int idx = i0;
  for (; idx + 4 <= i1; idx += 4) {
    int s0 = slist[idx], s1 = slist[idx + 1], s2 = slist[idx + 2], s3 = slist[idx + 3];
    const unsigned short* kb0 = kv + (size_t)s0 * 512;
    const unsigned short* kb1 = kv + (size_t)s1 * 512;
    const unsigned short* kb2 = kv + (size_t)s2 * 512;
    const unsigned short* kb3 = kv + (size_t)s3 * 512;
    union { uint2 u; unsigned short h[4]; } kk0, vv0, kk1, vv1, kk2, vv2, kk3, vv3;
    kk0.u = *(const uint2*)(kb0 + 4 * lane); vv0.u = *(const uint2*)(kb0 + 256 + 4 * lane);
    kk1.u = *(const uint2*)(kb1 + 4 * lane); vv1.u = *(const uint2*)(kb1 + 256 + 4 * lane);
    kk2.u = *(const uint2*)(kb2 + 4 * lane); vv2.u = *(const uint2*)(kb2 + 256 + 4 * lane);
    kk3.u = *(const uint2*)(kb3 + 4 * lane); vv3.u = *(const uint2*)(kb3 + 256 + 4 * lane);
    float d0 = q0 * bf2f(kk0.h[0]) + q1 * bf2f(kk0.h[1]) + q2 * bf2f(kk0.h[2]) + q3 * bf2f(kk0.h[3]);
    float d1 = q0 * bf2f(kk1.h[0]) + q1 * bf2f(kk1.h[1]) + q2 * bf2f(kk1.h[2]) + q3 * bf2f(kk1.h[3]);
    float d2 = q0 * bf2f(kk2.h[0]) + q1 * bf2f(kk2.h[1]) + q2 * bf2f(kk2.h[2]) + q3 * bf2f(kk2.h[3]);
    float d3 = q0 * bf2f(kk3.h[0]) + q1 * bf2f(kk3.h[1]) + q2 * bf2f(kk3.h[2]) + q3 * bf2f(kk3.h[3]);
#pragma unroll
    for (int dd = 1; dd < 16; dd <<= 1) {
      d0 += __shfl_xor(d0, dd);
      d1 += __shfl_xor(d1, dd);
      d2 += __shfl_xor(d2, dd);
      d3 += __shfl_xor(d3, dd);
    }
    float p0 = __expf(d0 * 0.125f);
    float p1 = __expf(d1 * 0.125f);
    float p2 = __expf(d2 * 0.125f);
    float p3 = __expf(d3 * 0.125f);
    lsum += p0 + p1 + p2 + p3;
    a0 = fmaf(p0, bf2f(vv0.h[0]), a0); a1 = fmaf(p0, bf2f(vv0.h[1]), a1);
    a2 = fmaf(p0, bf2f(vv0.h[2]), a2); a3 = fmaf(p0, bf2f(vv0.h[3]), a3);
    a0 = fmaf(p1, bf2f(vv1.h[0]), a0); a1 = fmaf(p1, bf2f(vv1.h[1]), a1);
    a2 = fmaf(p1, bf2f(vv1.h[2]), a2); a3 = fmaf(p1, bf2f(vv1.h[3]), a3);
    a0 = fmaf(p2, bf2f(vv2.h[0]), a0); a1 = fmaf(p2, bf2f(vv2.h[1]), a1);
    a2 = fmaf(p2, bf2f(vv2.h[2]), a2); a3 = fmaf(p2, bf2f(vv2.h[3]), a3);
    a0 = fmaf(p3, bf2f(vv3.h[0]), a0); a1 = fmaf(p3, bf2f(vv3.h[1]), a1);
    a2 = fmaf(p3, bf2f(vv3.h[2]), a2); a3 = fmaf(p3, bf2f(vv3.h[3]), a3);
  }
  for (; idx < i1; ++idx) {
    int s = slist[idx];
    const unsigned short* kb = kv + (size_t)s * 512;
    union { uint2 u; unsigned short h[4]; } kk, vv;
    kk.u = *(const uint2*)(kb + 4 * lane);
    vv.u = *(const uint2*)(kb + 256 + 4 * lane);
    float d = q0 * bf2f(kk.h[0]) + q1 * bf2f(kk.h[1]) + q2 * bf2f(kk.h[2]) + q3 * bf2f(kk.h[3]);
#pragma unroll
    for (int dd = 1; dd < 16; dd <<= 1) d += __shfl_xor(d, dd);
    float p = __expf(d * 0.125f);
    lsum += p;
    a0 = fmaf(p, bf2f(vv.h[0]), a0);
    a1 = fmaf(p, bf2f(vv.h[1]), a1);
    a2 = fmaf(p, bf2f(vv.h[2]), a2);
    a3 = fmaf(p, bf2f(vv.h[3]), a3);
  }
  union { uint2 u; unsigned short h[4]; } sb;
  sb.u = *(const uint2*)(skipb + (size_t)n * 256 + 4 * lane);
  float inv = (lsum > 0.f) ? 1.0f / lsum : 0.f;
  float v0 = bf2f(sb.h[0]) + a0 * inv;
  float v1 = bf2f(sb.h[1]) + a1 * inv;
  float v2 = bf2f(sb.h[2]) + a2 * inv;
  float v3 = bf2f(sb.h[3]) + a3 * inv;
  float s1 = wsum(v0 + v1 + v2 + v3);
  float s2 = wsum(v0 * v0 + v1 * v1 + v2 * v2 + v3 * v3);
  float mu = s1 * (1.0f / 256.0f);
  float var = s2 * (1.0f / 256.0f) - mu * mu;
  float rs = rsqrtf(fmaxf(var, 0.0f) + LN_EPS);
  float4 g4 = *(const float4*)(g + 4 * lane);
  float4 b4 = *(const float4*)(b + 4 * lane);
  union { uint2 u; unsigned short h[4]; } ob;
  ob.h[0] = f2bf((v0 - mu) * rs * g4.x + b4.x);
  ob.h[1] = f2bf((v1 - mu) * rs * g4.y + b4.y);
  ob.h[2] = f2bf((v2 - mu) * rs * g4.z + b4.z);
  ob.h[3] = f2bf((v3 - mu) * rs * g4.w + b4.w);
  *(uint2*)(aob + (size_t)n * 256 + 4 * lane) = ob.u;
}

// ---------------- classifier pair kernel ----------------
__global__ __launch_bounds__(256) void k_clf_pair(const float* __restrict__ ABt, const float* __restrict__ ABb,
                                                  const int* __restrict__ ei, const float* __restrict__ bc1,
                                                  const float* __restrict__ Wc2, const float* __restrict__ bc2,
                                                  float* __restrict__ out, int E) {
  int e = blockIdx.x * 4 + (threadIdx.x >> 6);
  int lane = threadIdx.x & 63;
  if (e >= E) return;
  int s = ei[e], t = ei[E + e];
  float h = fmaxf(ABt[(size_t)s * 64 + lane] + ABb[(size_t)t * 64 + lane] + bc1[lane], 0.0f);
  float r = wsum(h * Wc2[lane]);
  if (lane == 0) out[e] = r + bc2[0];
}

// ============================================================================
extern "C" void kernel_launch(void* const* d_in, const int* in_sizes, int n_in,
                              void* d_out, int out_size, void* d_ws, size_t ws_size,
                              hipStream_t stream) {
  const float* x = (const float*)d_in[0];
  const float* edge_attr = (const float*)d_in[1];
  const int* ei = (const int*)d_in[2];
  const int* zk = (const int*)d_in[3];
  const float* z_table = (const float*)d_in[4];
  const float* W_node = (const float*)d_in[5];
  const float* b_node = (const float*)d_in[6];
  const float* W_edge = (const float*)d_in[7];
  const float* b_edge = (const float*)d_in[8];
  const float* cn_w1 = (const float*)d_in[9];
  const float* cn_b1 = (const float*)d_in[10];
  const float* cn_w2 = (const float*)d_in[11];
  const float* cn_b2 = (const float*)d_in[12];
  const float* cn_cw1 = (const float*)d_in[13];
  const float* cn_cb1 = (const float*)d_in[14];
  const float* cn_cw2 = (const float*)d_in[15];
  const float* cn_cb2 = (const float*)d_in[16];
  const float* ce_w1 = (const float*)d_in[17];
  const float* ce_b1 = (const float*)d_in[18];
  const float* ce_w2 = (const float*)d_in[19];
  const float* ce_b2 = (const float*)d_in[20];
  const float* ce_cw1 = (const float*)d_in[21];
  const float* ce_cb1 = (const float*)d_in[22];
  const float* ce_cw2 = (const float*)d_in[23];
  const float* ce_cb2 = (const float*)d_in[24];
  const float* ln_comb_g = (const float*)d_in[25];
  const float* ln_comb_b = (const float*)d_in[26];
  const float* Wq = (const float*)d_in[27];
  const float* bq = (const float*)d_in[28];
  const float* Wk = (const float*)d_in[29];
  const float* bk = (const float*)d_in[30];
  const float* Wv = (const float*)d_in[31];
  const float* bv = (const float*)d_in[32];
  const float* Wskip = (const float*)d_in[33];
  const float* bskip = (const float*)d_in[34];
  const float* ln_tc_g = (const float*)d_in[35];
  const float* ln_tc_b = (const float*)d_in[36];
  const float* Wpn = (const float*)d_in[37];
  const float* bpn = (const float*)d_in[38];
  const float* Wpe = (const float*)d_in[39];
  const float* bpe = (const float*)d_in[40];
  const float* Wg = (const float*)d_in[41];
  const float* bg = (const float*)d_in[42];
  const float* Wc1 = (const float*)d_in[43];
  const float* bc1 = (const float*)d_in[44];
  const float* Wc2 = (const float*)d_in[45];
  const float* bc2 = (const float*)d_in[46];
  float* out = (float*)d_out;

  const int N = in_sizes[0] / 6;   // 50000
  const int E = in_sizes[2] / 2;   // 100000
  const int E2 = 2 * E;

  // ---- workspace carve (~216 MB peak) ----
  char* p = (char*)d_ws;
  auto carve = [&](size_t bytes) -> void* {
    void* r = (void*)p;
    p += (bytes + 255) & ~(size_t)255;
    return r;
  };
  unsigned short* qo = (unsigned short*)carve((size_t)N * 256 * 2);
  unsigned short* skipb = (unsigned short*)carve((size_t)N * 256 * 2); // skip -> Pe[N,128] alias
  unsigned short* kvb = (unsigned short*)carve((size_t)N * 512 * 2);
  unsigned short* aob = (unsigned short*)carve((size_t)N * 256 * 2);   // attn out -> AB f32
  unsigned short* efb = (unsigned short*)carve((size_t)E2 * 64 * 2);
  unsigned short* efc = (unsigned short*)carve((size_t)E2 * 64 * 2);
  float* nf = (float*)carve((size_t)N * 64 * 4);
  unsigned short* comb = (unsigned short*)carve((size_t)N * 128 * 2);
  unsigned short* W1t = (unsigned short*)carve((size_t)3 * 1024 * 128 * 2);
  float* bias1 = (float*)carve((size_t)3 * 1024 * 4);
  unsigned short* B2t = (unsigned short*)carve((size_t)3 * 256 * 256 * 2);
  float* bias2 = (float*)carve((size_t)3 * 256 * 4);
  unsigned short* Wg1t = (unsigned short*)carve((size_t)3 * 64 * 64 * 2);
  unsigned short* Wc1t = (unsigned short*)carve((size_t)2 * 64 * 64 * 2);
  int* cnt = (int*)carve((size_t)N * 4);
  int* cur = (int*)carve((size_t)N * 4);
  int* off = (int*)carve((size_t)(N + 1) * 4);
  int* pinv = (int*)carve((size_t)E2 * 4);
  int* slist = (int*)carve((size_t)E2 * 4);
  int* bsum = (int*)carve((size_t)256 * 4);
  int* boff = (int*)carve((size_t)256 * 4);
  float* pm = (float*)carve((size_t)PBLK * 64 * 4);
  float* ps = (float*)carve((size_t)PBLK * 64 * 4);
  float* cwv = (float*)carve(64 * 4);
  float* spmax = (float*)carve((size_t)E2 * 4);
  float* spmean = (float*)carve((size_t)E2 * 4);
  float* sconv = (float*)carve((size_t)E2 * 4);
  size_t need = (size_t)(p - (char*)d_ws);

  unsigned short* Pe = skipb;       // Pe [N,128] bf16 aliases skipb
  float* ABt = (float*)aob;         // AB halves reuse aob (dead after loop)
  float* ABb = (float*)aob + (size_t)N * 64;

  auto cdiv = [](int a, int b) { return (a + b - 1) / b; };

  if (ws_size < need) {
    k_sentinel<<<cdiv(E, 256), 256, 0, stream>>>(out, E);
    return;
  }

  // ---- CSR by dst (multi-block scan) ----
  k_zero2<<<cdiv(N, 256), 256, 0, stream>>>(cnt, cur, N);
  k_hist<<<cdiv(E2, 256), 256, 0, stream>>>(ei, cnt, E);
  const int nblk = cdiv(N, 1024);
  k_scan1<<<nblk, 256, 0, stream>>>(cnt, off, bsum, N);
  k_scan2<<<1, 64, 0, stream>>>(bsum, boff, off, N, nblk);
  k_scan3<<<cdiv(N, 256), 256, 0, stream>>>(off, boff, N);
  k_scatter<<<cdiv(E2, 256), 256, 0, stream>>>(ei, off, cur, pinv, slist, E);

  // ---- pack weights (bf16 transposed) ----
  const int PACK = 3 * 1024 * 128 + 3 * 1024 + 3 * 256 * 256 + 3 * 256 + 3 * 64 * 64 + 2 * 64 * 64;
  k_packW<<<cdiv(PACK, 256), 256, 0, stream>>>(Wq, Wk, Wv, Wskip, bq, bk, bv, bskip,
                                               Wpn, Wpe, bpn, bpe, Wg, Wc1,
                                               W1t, bias1, B2t, bias2, Wg1t, Wc1t);

  // ---- embeddings ----
  k_node_embed<<<cdiv(N, 4), 256, 0, stream>>>(x, zk, z_table, W_node, b_node, nf, N);
  k_edge_embed<<<cdiv(E2, 4), 256, 0, stream>>>(x, edge_attr, ei, W_edge, b_edge, efb, E);

  // ---- CBAM: nodes (fp32, in place) then edges (bf16, scatter to CSR) ----
  k_pool_partial<float><<<PBLK, 256, 0, stream>>>(nf, N, pm, ps);
  k_pool_final<<<1, 256, 0, stream>>>(pm, ps, N, PBLK, cn_w1, cn_b1, cn_w2, cn_b2, cwv);
  k_chan_sp<float><<<cdiv(N, 16), 256, 0, stream>>>(nf, N, cwv, spmax, spmean);
  k_conv<<<cdiv(N, 256), 256, 0, stream>>>(spmax, spmean, N, cn_cw1, cn_cb1, cn_cw2, cn_cb2, sconv);
  k_row_scale<<<cdiv(N * 16, 256), 256, 0, stream>>>(nf, N, sconv);

  k_pool_partial<unsigned short><<<PBLK, 256, 0, stream>>>(efb, E2, pm, ps);
  k_pool_final<<<1, 256, 0, stream>>>(pm, ps, E2, PBLK, ce_w1, ce_b1, ce_w2, ce_b2, cwv);
  k_chan_sp<unsigned short><<<cdiv(E2, 16), 256, 0, stream>>>(efb, E2, cwv, spmax, spmean);
  k_conv<<<cdiv(E2, 256), 256, 0, stream>>>(spmax, spmean, E2, ce_cw1, ce_cb1, ce_cw2, ce_cb2, sconv);
  k_row_scale_perm<<<cdiv(E2 * 16, 256), 256, 0, stream>>>(efb, E2, sconv, pinv, efc);

  // ---- T = 3 message-passing iterations ----
  const int gqkvs = cdiv(N, 128) * 8;       // 1D, XCD-swizzled in-kernel
  const int gpp = cdiv(N, 128) * 2;         // paired 1D grid for gemm_p
  for (int i = 0; i < 3; ++i) {
    k_aggcomb<<<cdiv(N, 4), 256, 0, stream>>>(efc, nf, off, comb,
                                              ln_comb_g + (size_t)i * 128, ln_comb_b + (size_t)i * 128, N);
    gemm_mfma<<<gqkvs, 256, 0, stream>>>(comb, N, 128, W1t + (size_t)i * 131072,
                                         bias1 + (size_t)i * 1024, qo, kvb, skipb);
    k_attn<<<cdiv(N, 4), 256, 0, stream>>>(qo, kvb, skipb, off, slist, aob,
                                           ln_tc_g + (size_t)i * 256, ln_tc_b + (size_t)i * 256, N);
    gemm_p<<<gpp, 256, 0, stream>>>(aob, nf, N, B2t + (size_t)i * 65536,
                                    bias2 + (size_t)i * 256, Wg1t + (size_t)i * 4096,
                                    bg + (size_t)i * 64, Pe);
    gemm_gate<2><<<cdiv(E2, 128), 256, 0, stream>>>(efc, E2, Wg1t + (size_t)i * 4096, Pe,
                                                    bg + (size_t)i * 64, slist, efc);
  }

  // ---- classifier: both halves in one launch (blockIdx.y) ----
  dim3 gclf(cdiv(N, 128), 2);
  gemm_gate<0><<<gclf, 256, 0, stream>>>(nf, N, Wc1t, nullptr, nullptr, nullptr, ABt);
  k_clf_pair<<<cdiv(E, 4), 256, 0, stream>>>(ABt, ABb, ei, bc1, Wc2, bc2, out, E);
  (void)out_size;
  (void)n_in;
}

// Round 15
// 699.544 us; speedup vs baseline: 1.0096x; 1.0096x over previous
//
#include <hip/hip_runtime.h>

// ============================================================================
// New_LinkNet GNN forward — MFMA bf16 GEMMs + fused gate updates.
// Round-15: REVERT to round-13 configuration (measured best: 698us).
// Round-14's gemm_p XCD-pairing caused per-XCD load imbalance (node blocks
// heavier than edge blocks) and the classifier fusion was neutral -> both
// backed out. This is the final consolidated version:
//   - MFMA bf16 GEMMs everywhere (QKVS fused NC=1024, XCD-swizzled;
//     P GEMM fused with node gate; edge gate GEMM with fused update)
//   - bf16 state end-to-end (Q/K/V/skip/P/ef/comb), fp32 nf
//   - CSR-ordered edge features (streaming aggregation, no gather)
//   - attention: 4-edge unrolled no-max softmax, wide coalesced gathers
//   - multi-block scan, vectorized CBAM, LDS-staged GEMM epilogues
// ============================================================================

#define LN_EPS 1e-5f
#define PBLK 512

typedef __attribute__((ext_vector_type(8))) short bf16x8;
typedef __attribute__((ext_vector_type(4))) float f32x4;

static __device__ __forceinline__ float wsum(float v) {
#pragma unroll
  for (int d = 32; d > 0; d >>= 1) v += __shfl_xor(v, d);
  return v;
}
static __device__ __forceinline__ float sigm(float x) { return 1.0f / (1.0f + __expf(-x)); }
static __device__ __forceinline__ unsigned short f2bf(float f) {
  unsigned int u = __float_as_uint(f);
  u += 0x7FFFu + ((u >> 16) & 1u);
  return (unsigned short)(u >> 16);
}
static __device__ __forceinline__ float bf2f(unsigned short b) {
  return __uint_as_float(((unsigned int)b) << 16);
}
static __device__ __forceinline__ float4 ld4v(const float* p) { return *(const float4*)p; }
static __device__ __forceinline__ float4 ld4v(const unsigned short* p) {
  union { uint2 u; unsigned short h[4]; } t;
  t.u = *(const uint2*)p;
  return make_float4(bf2f(t.h[0]), bf2f(t.h[1]), bf2f(t.h[2]), bf2f(t.h[3]));
}
static __device__ __forceinline__ void st4v(float* p, float4 v) { *(float4*)p = v; }
static __device__ __forceinline__ void st4v(unsigned short* p, float4 v) {
  union { uint2 u; unsigned short h[4]; } t;
  t.h[0] = f2bf(v.x); t.h[1] = f2bf(v.y); t.h[2] = f2bf(v.z); t.h[3] = f2bf(v.w);
  *(uint2*)p = t.u;
}

// ---------------- util ----------------
__global__ __launch_bounds__(256) void k_zero2(int* __restrict__ a, int* __restrict__ b, int n) {
  int i = blockIdx.x * 256 + threadIdx.x;
  if (i < n) { a[i] = 0; b[i] = 0; }
}

__global__ __launch_bounds__(256) void k_sentinel(float* __restrict__ out, int n) {
  int i = blockIdx.x * 256 + threadIdx.x;
  if (i < n) out[i] = 1.0e6f;
}

// ---------------- CSR build (by dst) ----------------
__global__ __launch_bounds__(256) void k_hist(const int* __restrict__ ei, int* __restrict__ cnt, int E) {
  int e = blockIdx.x * 256 + threadIdx.x;
  if (e >= 2 * E) return;
  int d = (e < E) ? ei[E + e] : ei[e - E];
  atomicAdd(&cnt[d], 1);
}

__global__ __launch_bounds__(256) void k_scan1(const int* __restrict__ cnt, int* __restrict__ off,
                                               int* __restrict__ bsum, int n) {
  const int t = threadIdx.x;
  const int lane = t & 63, w = t >> 6;
  const int i0 = blockIdx.x * 1024 + t * 4;
  int v0 = (i0 + 0 < n) ? cnt[i0 + 0] : 0;
  int v1 = (i0 + 1 < n) ? cnt[i0 + 1] : 0;
  int v2 = (i0 + 2 < n) ? cnt[i0 + 2] : 0;
  int v3 = (i0 + 3 < n) ? cnt[i0 + 3] : 0;
  int s = v0 + v1 + v2 + v3;
  int sc = s;
#pragma unroll
  for (int d = 1; d < 64; d <<= 1) {
    int tv = __shfl_up(sc, d);
    if (lane >= d) sc += tv;
  }
  __shared__ int wsums[4];
  if (lane == 63) wsums[w] = sc;
  __syncthreads();
  int wbase = 0;
#pragma unroll
  for (int k = 0; k < 4; ++k)
    if (k < w) wbase += wsums[k];
  int run = wbase + sc - s;
  if (i0 + 0 < n) off[i0 + 0] = run; run += v0;
  if (i0 + 1 < n) off[i0 + 1] = run; run += v1;
  if (i0 + 2 < n) off[i0 + 2] = run; run += v2;
  if (i0 + 3 < n) off[i0 + 3] = run;
  if (t == 255) bsum[blockIdx.x] = wbase + sc;
}

__global__ __launch_bounds__(64) void k_scan2(const int* __restrict__ bsum, int* __restrict__ boff,
                                              int* __restrict__ off, int n, int nblk) {
  const int lane = threadIdx.x;
  int carry = 0;
  for (int base = 0; base < nblk; base += 64) {
    int i = base + lane;
    int v = (i < nblk) ? bsum[i] : 0;
    int sc = v;
#pragma unroll
    for (int d = 1; d < 64; d <<= 1) {
      int tv = __shfl_up(sc, d);
      if (lane >= d) sc += tv;
    }
    if (i < nblk) boff[i] = carry + sc - v;
    carry += __shfl(sc, 63);
  }
  if (lane == 0) off[n] = carry;
}

__global__ __launch_bounds__(256) void k_scan3(int* __restrict__ off, const int* __restrict__ boff, int n) {
  int i = blockIdx.x * 256 + threadIdx.x;
  if (i < n) off[i] += boff[i >> 10];
}

__global__ __launch_bounds__(256) void k_scatter(const int* __restrict__ ei, const int* __restrict__ off,
                                                 int* __restrict__ cur, int* __restrict__ pinv,
                                                 int* __restrict__ slist, int E) {
  int e = blockIdx.x * 256 + threadIdx.x;
  if (e >= 2 * E) return;
  int d = (e < E) ? ei[E + e] : ei[e - E];
  int pos = atomicAdd(&cur[d], 1);
  int base = off[d] + pos;
  pinv[e] = base;
  slist[base] = ei[e];
}

// ---------------- pack all transposed bf16 weights ----------------
// B2 col order: [npj | vn | pe | ve]
__global__ __launch_bounds__(256) void k_packW(
    const float* __restrict__ Wq, const float* __restrict__ Wk, const float* __restrict__ Wv,
    const float* __restrict__ Ws, const float* __restrict__ bq, const float* __restrict__ bk,
    const float* __restrict__ bv, const float* __restrict__ bs,
    const float* __restrict__ Wpn, const float* __restrict__ Wpe,
    const float* __restrict__ bpn, const float* __restrict__ bpe,
    const float* __restrict__ Wg, const float* __restrict__ Wc1,
    unsigned short* __restrict__ W1t, float* __restrict__ bias1,
    unsigned short* __restrict__ B2t, float* __restrict__ bias2,
    unsigned short* __restrict__ Wg1t, unsigned short* __restrict__ Wc1t) {
  const int S1 = 3 * 1024 * 128, S2 = 3 * 1024, S3 = 3 * 256 * 256, S4 = 3 * 256;
  const int S5 = 3 * 64 * 64, S6 = 2 * 64 * 64;
  int idx = blockIdx.x * 256 + threadIdx.x;
  if (idx < S1) {
    int i = idx / 131072, r = idx % 131072;
    int col = r >> 7, k = r & 127;
    int m = col >> 8, cc = col & 255;
    const float* W = (m == 0) ? Wq : (m == 1) ? Wk : (m == 2) ? Wv : Ws;
    W1t[idx] = f2bf(W[i * 32768 + k * 256 + cc]);
  } else if (idx < S1 + S2) {
    int j = idx - S1;
    int i = j >> 10, col = j & 1023;
    int m = col >> 8, cc = col & 255;
    const float* bsrc = (m == 0) ? bq : (m == 1) ? bk : (m == 2) ? bv : bs;
    bias1[j] = bsrc[i * 256 + cc];
  } else if (idx < S1 + S2 + S3) {
    int j = idx - S1 - S2;
    int i = j / 65536, r = j % 65536;
    int col = r >> 8, k = r & 255;
    int half = col >> 6, cc = col & 63;
    float v;
    if (half == 0) v = Wpn[i * 16384 + k * 64 + cc];
    else if (half == 2) v = Wpe[i * 16384 + k * 64 + cc];
    else {
      const float* Wsrc = (half == 1) ? Wpn : Wpe;
      float acc = 0.f;
      for (int jj = 0; jj < 64; ++jj)
        acc = fmaf(Wsrc[i * 16384 + k * 64 + jj], Wg[i * 8192 + (64 + jj) * 64 + cc], acc);
      v = acc;
    }
    B2t[j] = f2bf(v);
  } else if (idx < S1 + S2 + S3 + S4) {
    int j = idx - S1 - S2 - S3;
    int i = j >> 8, col = j & 255;
    int half = col >> 6, cc = col & 63;
    float v;
    if (half == 0) v = bpn[i * 64 + cc];
    else if (half == 2) v = bpe[i * 64 + cc];
    else {
      const float* bsrc = (half == 1) ? bpn : bpe;
      float acc = 0.f;
      for (int jj = 0; jj < 64; ++jj)
        acc = fmaf(bsrc[i * 64 + jj], Wg[i * 8192 + (64 + jj) * 64 + cc], acc);
      v = acc;
    }
    bias2[j] = v;
  } else if (idx < S1 + S2 + S3 + S4 + S5) {
    int j = idx - S1 - S2 - S3 - S4;
    int i = j / 4096, r = j % 4096;
    int col = r >> 6, k = r & 63;
    Wg1t[j] = f2bf(Wg[i * 8192 + k * 64 + col]);
  } else if (idx < S1 + S2 + S3 + S4 + S5 + S6) {
    int j = idx - S1 - S2 - S3 - S4 - S5;
    int h = j / 4096, r = j % 4096;
    int col = r >> 6, k = r & 63;
    Wc1t[j] = f2bf(Wc1[(h * 64 + k) * 64 + col]);
  }
}

// ---------------- embeddings ----------------
__global__ __launch_bounds__(256) void k_node_embed(
    const float* __restrict__ x, const int* __restrict__ zk, const float* __restrict__ zt,
    const float* __restrict__ Wn, const float* __restrict__ bn, float* __restrict__ nf, int N) {
  int n = blockIdx.x * 4 + (threadIdx.x >> 6);
  int lane = threadIdx.x & 63;
  if (n >= N) return;
  const float* xr = x + (size_t)n * 6;
  float acc = bn[lane];
#pragma unroll
  for (int d = 0; d < 6; ++d) acc = fmaf(xr[d], Wn[d * 64 + lane], acc);
  int zi = __float2int_rn(xr[2]);
  int idx = 0;
#pragma unroll
  for (int t = 5; t >= 0; --t)
    if (zi == zk[t]) idx = t;
  nf[(size_t)n * 64 + lane] = fmaxf(acc, 0.0f) + zt[idx * 64 + lane];
}

__global__ __launch_bounds__(256) void k_edge_embed(
    const float* __restrict__ x, const float* __restrict__ ea, const int* __restrict__ ei,
    const float* __restrict__ We, const float* __restrict__ be,
    unsigned short* __restrict__ ef, int E) {
  int e = blockIdx.x * 4 + (threadIdx.x >> 6);
  int lane = threadIdx.x & 63;
  if (e >= 2 * E) return;
  int e0 = (e < E) ? e : e - E;
  int s = ei[e];
  int d = (e < E) ? ei[E + e] : ei[e - E];
  const float* ar = ea + (size_t)e0 * 4;
  const float* xs = x + (size_t)s * 6;
  const float* xd = x + (size_t)d * 6;
  float in[7];
  in[0] = ar[0]; in[1] = ar[1]; in[2] = ar[2]; in[3] = ar[3];
  in[4] = xs[0] - xd[0]; in[5] = xs[1] - xd[1]; in[6] = xs[2] - xd[2];
  float acc = be[lane];
#pragma unroll
  for (int dd = 0; dd < 7; ++dd) acc = fmaf(in[dd], We[dd * 64 + lane], acc);
  ef[(size_t)e * 64 + lane] = f2bf(fmaxf(acc, 0.0f));
}

// ---------------- CBAM (vectorized, fp32 or bf16 buffer) ----------------
template <typename T>
__global__ __launch_bounds__(256) void k_pool_partial(const T* __restrict__ buf, int n,
                                                      float* __restrict__ pm, float* __restrict__ ps) {
  const int w = threadIdx.x >> 6, l = threadIdx.x & 63;
  const int rsub = l >> 4, c4 = (l & 15) << 2;
  float4 mx = make_float4(-INFINITY, -INFINITY, -INFINITY, -INFINITY);
  float4 sm = make_float4(0.f, 0.f, 0.f, 0.f);
  for (int r = blockIdx.x * 16 + w * 4 + rsub; r < n; r += gridDim.x * 16) {
    float4 v = ld4v(buf + (size_t)r * 64 + c4);
    mx.x = fmaxf(mx.x, v.x); mx.y = fmaxf(mx.y, v.y);
    mx.z = fmaxf(mx.z, v.z); mx.w = fmaxf(mx.w, v.w);
    sm.x += v.x; sm.y += v.y; sm.z += v.z; sm.w += v.w;
  }
#pragma unroll
  for (int d = 16; d < 64; d <<= 1) {
    mx.x = fmaxf(mx.x, __shfl_xor(mx.x, d)); mx.y = fmaxf(mx.y, __shfl_xor(mx.y, d));
    mx.z = fmaxf(mx.z, __shfl_xor(mx.z, d)); mx.w = fmaxf(mx.w, __shfl_xor(mx.w, d));
    sm.x += __shfl_xor(sm.x, d); sm.y += __shfl_xor(sm.y, d);
    sm.z += __shfl_xor(sm.z, d); sm.w += __shfl_xor(sm.w, d);
  }
  __shared__ float smx[4][64], ssm[4][64];
  if (l < 16) {
    *(float4*)&smx[w][c4] = mx;
    *(float4*)&ssm[w][c4] = sm;
  }
  __syncthreads();
  if (threadIdx.x < 64) {
    int t = threadIdx.x;
    float m2 = fmaxf(fmaxf(smx[0][t], smx[1][t]), fmaxf(smx[2][t], smx[3][t]));
    float s2 = ssm[0][t] + ssm[1][t] + ssm[2][t] + ssm[3][t];
    pm[blockIdx.x * 64 + t] = m2;
    ps[blockIdx.x * 64 + t] = s2;
  }
}

__global__ __launch_bounds__(256) void k_pool_final(
    const float* __restrict__ pm, const float* __restrict__ ps, int n, int nblk,
    const float* __restrict__ w1, const float* __restrict__ b1,
    const float* __restrict__ w2, const float* __restrict__ b2, float* __restrict__ cw) {
  __shared__ float redm[4][64], reds[4][64];
  __shared__ float cat[128];
  __shared__ float hid[4];
  int t = threadIdx.x;
  int g = t >> 6, col = t & 63;
  float mx = -INFINITY, sm = 0.0f;
  for (int p = g; p < nblk; p += 4) {
    mx = fmaxf(mx, pm[p * 64 + col]);
    sm += ps[p * 64 + col];
  }
  redm[g][col] = mx;
  reds[g][col] = sm;
  __syncthreads();
  if (t < 64) {
    float m2 = fmaxf(fmaxf(redm[0][t], redm[1][t]), fmaxf(redm[2][t], redm[3][t]));
    float s2 = reds[0][t] + reds[1][t] + reds[2][t] + reds[3][t];
    cat[t] = m2;
    cat[64 + t] = s2 / (float)n;
  }
  __syncthreads();
  if (t < 4) {
    float a = b1[t];
    for (int k = 0; k < 128; ++k) a = fmaf(cat[k], w1[k * 4 + t], a);
    hid[t] = fmaxf(a, 0.0f);
  }
  __syncthreads();
  if (t < 64) {
    float a = b2[t];
#pragma unroll
    for (int h = 0; h < 4; ++h) a = fmaf(hid[h], w2[h * 64 + t], a);
    cw[t] = sigm(a);
  }
}

template <typename T>
__global__ __launch_bounds__(256) void k_chan_sp(T* __restrict__ buf, int n,
                                                 const float* __restrict__ cw,
                                                 float* __restrict__ spmax, float* __restrict__ spmean) {
  const int w = threadIdx.x >> 6, l = threadIdx.x & 63;
  const int rsub = l >> 4, c4 = (l & 15) << 2;
  int r = blockIdx.x * 16 + w * 4 + rsub;
  if (r >= n) return;
  float4 cwv = *(const float4*)(cw + c4);
  float4 v = ld4v(buf + (size_t)r * 64 + c4);
  v.x *= cwv.x; v.y *= cwv.y; v.z *= cwv.z; v.w *= cwv.w;
  st4v(buf + (size_t)r * 64 + c4, v);
  float mx = fmaxf(fmaxf(v.x, v.y), fmaxf(v.z, v.w));
  float sm = v.x + v.y + v.z + v.w;
#pragma unroll
  for (int d = 1; d < 16; d <<= 1) {
    mx = fmaxf(mx, __shfl_xor(mx, d));
    sm += __shfl_xor(sm, d);
  }
  if ((l & 15) == 0) {
    spmax[r] = mx;
    spmean[r] = sm * (1.0f / 64.0f);
  }
}

__global__ __launch_bounds__(256) void k_conv(const float* __restrict__ spmax, const float* __restrict__ spmean,
                                              int n, const float* __restrict__ w1, const float* __restrict__ b1,
                                              const float* __restrict__ w2, const float* __restrict__ b2,
                                              float* __restrict__ s) {
  __shared__ float tl[258];
  int base = blockIdx.x * 256;
  for (int q = threadIdx.x; q < 258; q += 256) {
    int p = base - 1 + q;
    float t = 0.0f;
    if (p >= 0 && p < n) {
      float a = b1[0];
#pragma unroll
      for (int h = 0; h < 5; ++h) {
        int pp = p + h - 2;
        if (pp >= 0 && pp < n) a += spmax[pp] * w1[h] + spmean[pp] * w1[5 + h];
      }
      t = fmaxf(a, 0.0f);
    }
    tl[q] = t;
  }
  __syncthreads();
  int o = base + threadIdx.x;
  if (o < n) {
    float a = b2[0] + tl[threadIdx.x] * w2[0] + tl[threadIdx.x + 1] * w2[1] + tl[threadIdx.x + 2] * w2[2];
    s[o] = sigm(a);
  }
}

__global__ __launch_bounds__(256) void k_row_scale(float* __restrict__ buf, int n, const float* __restrict__ s) {
  int i4 = blockIdx.x * 256 + threadIdx.x;
  if (i4 >= n * 16) return;
  int r = i4 >> 4;
  float sc = s[r];
  float4 v = ld4v(buf + (size_t)i4 * 4);
  v.x *= sc; v.y *= sc; v.z *= sc; v.w *= sc;
  st4v(buf + (size_t)i4 * 4, v);
}

__global__ __launch_bounds__(256) void k_row_scale_perm(const unsigned short* __restrict__ src, int n,
                                                        const float* __restrict__ s,
                                                        const int* __restrict__ pinv,
                                                        unsigned short* __restrict__ dst) {
  int i4 = blockIdx.x * 256 + threadIdx.x;
  if (i4 >= n * 16) return;
  int r = i4 >> 4, c4 = (i4 & 15) * 4;
  float sc = s[r];
  float4 v = ld4v(src + (size_t)r * 64 + c4);
  v.x *= sc; v.y *= sc; v.z *= sc; v.w *= sc;
  st4v(dst + (size_t)pinv[r] * 64 + c4, v);
}

// ---------------- agg + concat-LN (CSR-ordered bf16 ef, streaming) --------
__global__ __launch_bounds__(256) void k_aggcomb(const unsigned short* __restrict__ efc,
                                                 const float* __restrict__ nf,
                                                 const int* __restrict__ off,
                                                 unsigned short* __restrict__ comb, const float* __restrict__ g,
                                                 const float* __restrict__ b, int N) {
  int n = blockIdx.x * 4 + (threadIdx.x >> 6);
  int lane = threadIdx.x & 63;
  if (n >= N) return;
  float agg = 0.0f;
  int i0 = off[n], i1 = off[n + 1];
  for (int idx = i0; idx < i1; ++idx) agg += bf2f(efc[(size_t)idx * 64 + lane]);
  float y0 = nf[(size_t)n * 64 + lane];
  float y1 = agg - y0;
  float s1 = wsum(y0 + y1);
  float s2 = wsum(y0 * y0 + y1 * y1);
  float mu = s1 * (1.0f / 128.0f);
  float var = s2 * (1.0f / 128.0f) - mu * mu;
  float rs = rsqrtf(fmaxf(var, 0.0f) + LN_EPS);
  comb[(size_t)n * 128 + lane] = f2bf((y0 - mu) * rs * g[lane] + b[lane]);
  comb[(size_t)n * 128 + 64 + lane] = f2bf((y1 - mu) * rs * g[64 + lane] + b[64 + lane]);
}

// ---------------- MFMA GEMM: QKVS (XCD-swizzled) --------------------------
__global__ __launch_bounds__(256) void gemm_mfma(
    const unsigned short* __restrict__ A, int M, int K,
    const unsigned short* __restrict__ Bt, const float* __restrict__ bias,
    unsigned short* __restrict__ outQ, unsigned short* __restrict__ outK,
    unsigned short* __restrict__ outS) {
  __shared__ unsigned short shmem[128 * 136];
  unsigned short* As = shmem;
  unsigned short* Bs = shmem + 128 * 64;
  const int tid = threadIdx.x;
  int cpx = gridDim.x >> 3;
  int wgid = (blockIdx.x & 7) * cpx + (blockIdx.x >> 3);
  int bm = (wgid >> 3) * 128;
  int bn = (wgid & 7) * 128;
  const int wid = tid >> 6, lane = tid & 63;
  const int wr = (wid >> 1) * 64, wc = (wid & 1) * 64;
  const int lrow = lane & 15, lkb = (lane >> 4) * 8;
  f32x4 acc[4][4];
#pragma unroll
  for (int m = 0; m < 4; ++m)
#pragma unroll
    for (int n = 0; n < 4; ++n) acc[m][n] = (f32x4){0.f, 0.f, 0.f, 0.f};

  for (int k0 = 0; k0 < K; k0 += 64) {
#pragma unroll
    for (int l = 0; l < 4; ++l) {
      int c = tid + l * 256;
      int row = c >> 3, kc = (c & 7) * 8;
      int sw = row * 64 + (kc ^ ((row & 7) << 3));
      int grow = bm + row;
      bf16x8 v = {0, 0, 0, 0, 0, 0, 0, 0};
      if (grow < M) v = *(const bf16x8*)(A + (size_t)grow * K + k0 + kc);
      *(bf16x8*)&As[sw] = v;
      int gcol = bn + row;
      *(bf16x8*)&Bs[sw] = *(const bf16x8*)(Bt + (size_t)gcol * K + k0 + kc);
    }
    __syncthreads();
#pragma unroll
    for (int ks = 0; ks < 2; ++ks) {
      const int ke = ks * 32 + lkb;
      bf16x8 af[4], bfr[4];
#pragma unroll
      for (int m = 0; m < 4; ++m) {
        int row = wr + m * 16 + lrow;
        af[m] = *(const bf16x8*)&As[row * 64 + (ke ^ ((row & 7) << 3))];
      }
#pragma unroll
      for (int n = 0; n < 4; ++n) {
        int col = wc + n * 16 + lrow;
        bfr[n] = *(const bf16x8*)&Bs[col * 64 + (ke ^ ((col & 7) << 3))];
      }
#pragma unroll
      for (int m = 0; m < 4; ++m)
#pragma unroll
        for (int n = 0; n < 4; ++n)
          acc[m][n] = __builtin_amdgcn_mfma_f32_16x16x32_bf16(af[m], bfr[n], acc[m][n], 0, 0, 0);
    }
    __syncthreads();
  }

  const int colw = lane & 15, rq = (lane >> 4) * 4;
  unsigned short* Cs = shmem;
#pragma unroll
  for (int m = 0; m < 4; ++m) {
#pragma unroll
    for (int n = 0; n < 4; ++n) {
      int col = wc + n * 16 + colw;
      float bv = bias[bn + col];
#pragma unroll
      for (int r = 0; r < 4; ++r) {
        int row = wr + m * 16 + rq + r;
        Cs[row * 136 + col] = f2bf(acc[m][n][r] + bv);
      }
    }
  }
  __syncthreads();
  const int rsub = tid >> 4, c8 = (tid & 15) * 8;
#pragma unroll
  for (int i = 0; i < 8; ++i) {
    int row = i * 16 + rsub;
    int grow = bm + row;
    if (grow >= M) continue;
    uint4 v = *(const uint4*)&Cs[row * 136 + c8];
    const int proj = bn >> 8;
    int cc = (bn & 255) + c8;
    if (proj == 0) *(uint4*)(outQ + (size_t)grow * 256 + cc) = v;
    else if (proj == 1) *(uint4*)(outK + (size_t)grow * 512 + cc) = v;
    else if (proj == 2) *(uint4*)(outK + (size_t)grow * 512 + 256 + cc) = v;
    else *(uint4*)(outS + (size_t)grow * 256 + cc) = v;
  }
}

// ---------- fused P GEMM: y=0 node path (P-node + Sn + gate update),
//            y=1 edge path (writes Pe[N,128]) --------------------------------
__global__ __launch_bounds__(256) void gemm_p(
    const unsigned short* __restrict__ aob, float* __restrict__ nf, int N,
    const unsigned short* __restrict__ B2t, const float* __restrict__ bias2,
    const unsigned short* __restrict__ Wg1t, const float* __restrict__ bgv,
    unsigned short* __restrict__ Pe) {
  __shared__ unsigned short shmem[128 * 136];
  unsigned short* As = shmem;
  unsigned short* Bs = shmem + 128 * 64;
  const int tid = threadIdx.x;
  const int bm = blockIdx.x * 128;
  const bool nodeblk = (blockIdx.y == 0);
  const int wid = tid >> 6, lane = tid & 63;
  const int lrow = lane & 15, lkb = (lane >> 4) * 8;

  f32x4 accS[2][4];
  if (nodeblk) {
    // Phase A: Sn = nf @ Wg1 (gate-style: wave wid owns rows wid*32..+32)
#pragma unroll
    for (int l = 0; l < 8; ++l) {
      int u = tid + l * 256;
      int row = u >> 4, k4 = (u & 15) << 2;
      int grow = bm + row;
      float4 v = make_float4(0.f, 0.f, 0.f, 0.f);
      if (grow < N) v = *(const float4*)(nf + (size_t)grow * 64 + k4);
      union { unsigned short h[4]; uint2 q2; } pk;
      pk.h[0] = f2bf(v.x); pk.h[1] = f2bf(v.y); pk.h[2] = f2bf(v.z); pk.h[3] = f2bf(v.w);
      *(uint2*)&As[row * 64 + (k4 ^ ((row & 7) << 3))] = pk.q2;
    }
#pragma unroll
    for (int l = 0; l < 2; ++l) {
      int u = tid + l * 256;
      int row = u >> 3, kc = (u & 7) * 8;
      *(bf16x8*)&Bs[row * 64 + (kc ^ ((row & 7) << 3))] = *(const bf16x8*)(Wg1t + row * 64 + kc);
    }
    __syncthreads();
    const int wrS = wid * 32;
#pragma unroll
    for (int m = 0; m < 2; ++m)
#pragma unroll
      for (int n = 0; n < 4; ++n) accS[m][n] = (f32x4){0.f, 0.f, 0.f, 0.f};
#pragma unroll
    for (int ks = 0; ks < 2; ++ks) {
      const int ke = ks * 32 + lkb;
      bf16x8 af[2], wf[4];
#pragma unroll
      for (int m = 0; m < 2; ++m) {
        int row = wrS + m * 16 + lrow;
        af[m] = *(const bf16x8*)&As[row * 64 + (ke ^ ((row & 7) << 3))];
      }
#pragma unroll
      for (int n = 0; n < 4; ++n) {
        int col = n * 16 + lrow;
        wf[n] = *(const bf16x8*)&Bs[col * 64 + (ke ^ ((col & 7) << 3))];
      }
#pragma unroll
      for (int m = 0; m < 2; ++m)
#pragma unroll
        for (int n = 0; n < 4; ++n)
          accS[m][n] = __builtin_amdgcn_mfma_f32_16x16x32_bf16(af[m], wf[n], accS[m][n], 0, 0, 0);
    }
    __syncthreads();
  }

  // Phase B: main GEMM over 128 cols (node: [npj|vn] rows 0-127 of B2t;
  // edge: [pe|ve] rows 128-255)
  const int cbase = nodeblk ? 0 : 128;
  const int wr = (wid >> 1) * 64, wc = (wid & 1) * 64;
  f32x4 acc[4][4];
#pragma unroll
  for (int m = 0; m < 4; ++m)
#pragma unroll
    for (int n = 0; n < 4; ++n) acc[m][n] = (f32x4){0.f, 0.f, 0.f, 0.f};
  for (int k0 = 0; k0 < 256; k0 += 64) {
#pragma unroll
    for (int l = 0; l < 4; ++l) {
      int c = tid + l * 256;
      int row = c >> 3, kc = (c & 7) * 8;
      int sw = row * 64 + (kc ^ ((row & 7) << 3));
      int grow = bm + row;
      bf16x8 v = {0, 0, 0, 0, 0, 0, 0, 0};
      if (grow < N) v = *(const bf16x8*)(aob + (size_t)grow * 256 + k0 + kc);
      *(bf16x8*)&As[sw] = v;
      *(bf16x8*)&Bs[sw] = *(const bf16x8*)(B2t + (size_t)(cbase + row) * 256 + k0 + kc);
    }
    __syncthreads();
#pragma unroll
    for (int ks = 0; ks < 2; ++ks) {
      const int ke = ks * 32 + lkb;
      bf16x8 af[4], bfr[4];
#pragma unroll
      for (int m = 0; m < 4; ++m) {
        int row = wr + m * 16 + lrow;
        af[m] = *(const bf16x8*)&As[row * 64 + (ke ^ ((row & 7) << 3))];
      }
#pragma unroll
      for (int n = 0; n < 4; ++n) {
        int col = wc + n * 16 + lrow;
        bfr[n] = *(const bf16x8*)&Bs[col * 64 + (ke ^ ((col & 7) << 3))];
      }
#pragma unroll
      for (int m = 0; m < 4; ++m)
#pragma unroll
        for (int n = 0; n < 4; ++n)
          acc[m][n] = __builtin_amdgcn_mfma_f32_16x16x32_bf16(af[m], bfr[n], acc[m][n], 0, 0, 0);
    }
    __syncthreads();
  }

  // Stage C tile (with bias) into LDS
  const int colw = lane & 15, rq = (lane >> 4) * 4;
  unsigned short* Cs = shmem;
#pragma unroll
  for (int m = 0; m < 4; ++m) {
#pragma unroll
    for (int n = 0; n < 4; ++n) {
      int col = wc + n * 16 + colw;
      float bv = bias2[cbase + col];
#pragma unroll
      for (int r = 0; r < 4; ++r) {
        int row = wr + m * 16 + rq + r;
        Cs[row * 136 + col] = f2bf(acc[m][n][r] + bv);
      }
    }
  }
  __syncthreads();

  if (nodeblk) {
    // node gate update: g = sigm(Sn + vn + bg); nf = nf*g + npj*(1-g)
    const int wrS = wid * 32;
#pragma unroll
    for (int m = 0; m < 2; ++m) {
#pragma unroll
      for (int r = 0; r < 4; ++r) {
        int row = wrS + m * 16 + rq + r;
        int grow = bm + row;
        if (grow >= N) continue;
#pragma unroll
        for (int n = 0; n < 4; ++n) {
          int c = n * 16 + colw;
          float g = sigm(accS[m][n][r] + bf2f(Cs[row * 136 + 64 + c]) + bgv[c]);
          size_t oi = (size_t)grow * 64 + c;
          float old = nf[oi];
          nf[oi] = old * g + bf2f(Cs[row * 136 + c]) * (1.0f - g);
        }
      }
    }
  } else {
    const int rsub = tid >> 4, c8 = (tid & 15) * 8;
#pragma unroll
    for (int i = 0; i < 8; ++i) {
      int row = i * 16 + rsub;
      int grow = bm + row;
      if (grow >= N) continue;
      *(uint4*)(Pe + (size_t)grow * 128 + c8) = *(const uint4*)&Cs[row * 136 + c8];
    }
  }
}

// ------ MFMA [M,64]@[64,64] with fused epilogue ------
// UPD 0: fp32 A, store fp32 C. UPD 2: bf16 A (efc), bf16 edge-gate update
// using Pe[N,128] (pe cols 0-63, ve cols 64-127); src from srcl.
template <int UPD>
__global__ __launch_bounds__(256) void gemm_gate(
    const void* __restrict__ Av, int M, const unsigned short* __restrict__ Wt,
    const unsigned short* __restrict__ P, const float* __restrict__ bgv,
    const int* __restrict__ srcl, void* __restrict__ updv) {
  __shared__ unsigned short As[128 * 64];
  __shared__ unsigned short Ws[64 * 64];
  const int tid = threadIdx.x;
  const int bm = blockIdx.x * 128;
  if (UPD == 2) {
    const unsigned short* Ab = (const unsigned short*)Av;
#pragma unroll
    for (int l = 0; l < 4; ++l) {
      int u = tid + l * 256;
      int row = u >> 3, kc = (u & 7) * 8;
      int grow = bm + row;
      bf16x8 v = {0, 0, 0, 0, 0, 0, 0, 0};
      if (grow < M) v = *(const bf16x8*)(Ab + (size_t)grow * 64 + kc);
      *(bf16x8*)&As[row * 64 + (kc ^ ((row & 7) << 3))] = v;
    }
  } else {
    const float* Af = (const float*)Av;
#pragma unroll
    for (int l = 0; l < 8; ++l) {
      int u = tid + l * 256;
      int row = u >> 4, k4 = (u & 15) << 2;
      int grow = bm + row;
      float4 v = make_float4(0.f, 0.f, 0.f, 0.f);
      if (grow < M) v = *(const float4*)(Af + (size_t)grow * 64 + k4);
      union { unsigned short h[4]; uint2 q; } pk;
      pk.h[0] = f2bf(v.x); pk.h[1] = f2bf(v.y); pk.h[2] = f2bf(v.z); pk.h[3] = f2bf(v.w);
      *(uint2*)&As[row * 64 + (k4 ^ ((row & 7) << 3))] = pk.q;
    }
  }
#pragma unroll
  for (int l = 0; l < 2; ++l) {
    int u = tid + l * 256;
    int row = u >> 3, kc = (u & 7) * 8;
    *(bf16x8*)&Ws[row * 64 + (kc ^ ((row & 7) << 3))] = *(const bf16x8*)(Wt + row * 64 + kc);
  }
  __syncthreads();
  const int wid = tid >> 6, lane = tid & 63;
  const int wr = wid * 32;
  const int lrow = lane & 15, lkb = (lane >> 4) * 8;
  f32x4 acc[2][4];
#pragma unroll
  for (int m = 0; m < 2; ++m)
#pragma unroll
    for (int n = 0; n < 4; ++n) acc[m][n] = (f32x4){0.f, 0.f, 0.f, 0.f};
#pragma unroll
  for (int ks = 0; ks < 2; ++ks) {
    const int ke = ks * 32 + lkb;
    bf16x8 af[2], wf[4];
#pragma unroll
    for (int m = 0; m < 2; ++m) {
      int row = wr + m * 16 + lrow;
      af[m] = *(const bf16x8*)&As[row * 64 + (ke ^ ((row & 7) << 3))];
    }
#pragma unroll
    for (int n = 0; n < 4; ++n) {
      int col = n * 16 + lrow;
      wf[n] = *(const bf16x8*)&Ws[col * 64 + (ke ^ ((col & 7) << 3))];
    }
#pragma unroll
    for (int m = 0; m < 2; ++m)
#pragma unroll
      for (int n = 0; n < 4; ++n)
        acc[m][n] = __builtin_amdgcn_mfma_f32_16x16x32_bf16(af[m], wf[n], acc[m][n], 0, 0, 0);
  }
  const int colw = lane & 15, rq = (lane >> 4) * 4;
#pragma unroll
  for (int m = 0; m < 2; ++m) {
#pragma unroll
    for (int r = 0; r < 4; ++r) {
      int e = bm + wr + m * 16 + rq + r;
      if (e >= M) continue;
      if (UPD == 0) {
        float* upd = (float*)updv;
#pragma unroll
        for (int n = 0; n < 4; ++n) upd[(size_t)e * 64 + n * 16 + colw] = acc[m][n][r];
      } else {
        unsigned short* upd = (unsigned short*)updv;
        int s = srcl[e];
        const unsigned short* Pr = P + (size_t)s * 128;
#pragma unroll
        for (int n = 0; n < 4; ++n) {
          int c = n * 16 + colw;
          float g = sigm(acc[m][n][r] + bf2f(Pr[64 + c]) + bgv[c]);
          size_t oi = (size_t)e * 64 + c;
          float vA = bf2f(upd[oi]);
          upd[oi] = f2bf(vA * g + bf2f(Pr[c]) * (1.0f - g));
        }
      }
    }
  }
}

// ---------------- attention: no-max softmax, 4-edge unrolled --------------
__global__ __launch_bounds__(256) void k_attn(const unsigned short* __restrict__ qo,
                                              const unsigned short* __restrict__ kv,
                                              const unsigned short* __restrict__ skipb, const int* __restrict__ off,
                                              const int* __restrict__ slist,
                                              unsigned short* __restrict__ aob,
                                              const float* __restrict__ g, const float* __restrict__ b, int N) {
  int n = blockIdx.x * 4 + (threadIdx.x >> 6);
  int lane = threadIdx.x & 63;
  if (n >= N) return;
  union { uint2 u; unsigned short h[4]; } qq;
  qq.u = *(const uint2*)(qo + (size_t)n * 256 + 4 * lane);
  float q0 = bf2f(qq.h[0]), q1 = bf2f(qq.h[1]), q2 = bf2f(qq.h[2]), q3 = bf2f(qq.h[3]);
  float lsum = 0.f;
  float a0 = 0.f, a1 = 0.f, a2 = 0.f, a3 = 0.f;
  int i0 = off[n], i1 = off[n + 1];
  int idx = i0;
  for (; idx + 4 <= i1; idx += 4) {
    int s0 = slist[idx], s1 = slist[idx + 1], s2 = slist[idx + 2], s3 = slist[idx + 3];
    const unsigned short* kb0 = kv + (size_t)s0 * 512;
    const unsigned short* kb1 = kv + (size_t)s1 * 512;
    const unsigned short* kb2 = kv + (size_t)s2 * 512;
    const unsigned short* kb3 = kv + (size_t)s3 * 512;
    union { uint2 u; unsigned short h[4]; } kk0, vv0, kk1, vv1, kk2, vv2, kk3, vv3;
    kk0.u = *(const uint2*)(kb0 + 4 * lane); vv0.u = *(const uint2*)(kb0 + 256 + 4 * lane);
    kk1.u = *(const uint2*)(kb1 + 4 * lane); vv1.u = *(const uint2*)(kb1 + 256 + 4 * lane);
    kk2.u = *(const uint2*)(kb2 + 4 * lane); vv2.u = *(const uint2*)(kb2 + 256 + 4 * lane);
    kk3.u = *(const uint2*)(kb3 + 4 * lane); vv3.u = *(const uint2*)(kb3 + 256 + 4 * lane);
    float d0 = q0 * bf2f(kk0.h[0]) + q1 * bf2f(kk0.h[1]) + q2 * bf2f(kk0.h[2]) + q3 * bf2f(kk0.h[3]);
    float d1 = q0 * bf2f(kk1.h[0]) + q1 * bf2f(kk1.h[1]) + q2 * bf2f(kk1.h[2]) + q3 * bf2f(kk1.h[3]);
    float d2 = q0 * bf2f(kk2.h[0]) + q1 * bf2f(kk2.h[1]) + q2 * bf2f(kk2.h[2]) + q3 * bf2f(kk2.h[3]);
    float d3 = q0 * bf2f(kk3.h[0]) + q1 * bf2f(kk3.h[1]) + q2 * bf2f(kk3.h[2]) + q3 * bf2f(kk3.h[3]);
#pragma unroll
    for (int dd = 1; dd < 16; dd <<= 1) {
      d0 += __shfl_xor(d0, dd);
      d1 += __shfl_xor(d1, dd);
      d2 += __shfl_xor(d2, dd);
      d3 += __shfl_xor(d3, dd);
    }
    float p0 = __expf(d0 * 0.125f);
    float p1 = __expf(d1 * 0.125f);
    float p2 = __expf(d2 * 0.125f);
    float p3 = __expf(d3 * 0.125f);
    lsum += p0 + p1 + p2 + p3;
    a0 = fmaf(p0, bf2f(vv0.h[0]), a0); a1 = fmaf(p0, bf2f(vv0.h[1]), a1);
    a2 = fmaf(p0, bf2f(vv0.h[2]), a2); a3 = fmaf(p0, bf2f(vv0.h[3]), a3);
    a0 = fmaf(p1, bf2f(vv1.h[0]), a0); a1 = fmaf(p1, bf2f(vv1.h[1]), a1);
    a2 = fmaf(p1, bf2f(vv1.h[2]), a2); a3 = fmaf(p1, bf2f(vv1.h[3]), a3);
    a0 = fmaf(p2, bf2f(vv2.h[0]), a0); a1 = fmaf(p2, bf2f(vv2.h[1]), a1);
    a2 = fmaf(p2, bf2f(vv2.h[2]), a2); a3 = fmaf(p2, bf2f(vv2.h[3]), a3);
    a0 = fmaf(p3, bf2f(vv3.h[0]), a0); a1 = fmaf(p3, bf2f(vv3.h[1]), a1);
    a2 = fmaf(p3, bf2f(vv3.h[2]), a2); a3 = fmaf(p3, bf2f(vv3.h[3]), a3);
  }
  for (; idx < i1; ++idx) {
    int s = slist[idx];
    const unsigned short* kb = kv + (size_t)s * 512;
    union { uint2 u; unsigned short h[4]; } kk, vv;
    kk.u = *(const uint2*)(kb + 4 * lane);
    vv.u = *(const uint2*)(kb + 256 + 4 * lane);
    float d = q0 * bf2f(kk.h[0]) + q1 * bf2f(kk.h[1]) + q2 * bf2f(kk.h[2]) + q3 * bf2f(kk.h[3]);
#pragma unroll
    for (int dd = 1; dd < 16; dd <<= 1) d += __shfl_xor(d, dd);
    float p = __expf(d * 0.125f);
    lsum += p;
    a0 = fmaf(p, bf2f(vv.h[0]), a0);
    a1 = fmaf(p, bf2f(vv.h[1]), a1);
    a2 = fmaf(p, bf2f(vv.h[2]), a2);
    a3 = fmaf(p, bf2f(vv.h[3]), a3);
  }
  union { uint2 u; unsigned short h[4]; } sb;
  sb.u = *(const uint2*)(skipb + (size_t)n * 256 + 4 * lane);
  float inv = (lsum > 0.f) ? 1.0f / lsum : 0.f;
  float v0 = bf2f(sb.h[0]) + a0 * inv;
  float v1 = bf2f(sb.h[1]) + a1 * inv;
  float v2 = bf2f(sb.h[2]) + a2 * inv;
  float v3 = bf2f(sb.h[3]) + a3 * inv;
  float s1 = wsum(v0 + v1 + v2 + v3);
  float s2 = wsum(v0 * v0 + v1 * v1 + v2 * v2 + v3 * v3);
  float mu = s1 * (1.0f / 256.0f);
  float var = s2 * (1.0f / 256.0f) - mu * mu;
  float rs = rsqrtf(fmaxf(var, 0.0f) + LN_EPS);
  float4 g4 = *(const float4*)(g + 4 * lane);
  float4 b4 = *(const float4*)(b + 4 * lane);
  union { uint2 u; unsigned short h[4]; } ob;
  ob.h[0] = f2bf((v0 - mu) * rs * g4.x + b4.x);
  ob.h[1] = f2bf((v1 - mu) * rs * g4.y + b4.y);
  ob.h[2] = f2bf((v2 - mu) * rs * g4.z + b4.z);
  ob.h[3] = f2bf((v3 - mu) * rs * g4.w + b4.w);
  *(uint2*)(aob + (size_t)n * 256 + 4 * lane) = ob.u;
}

// ---------------- classifier pair kernel ----------------
__global__ __launch_bounds__(256) void k_clf_pair(const float* __restrict__ ABt, const float* __restrict__ ABb,
                                                  const int* __restrict__ ei, const float* __restrict__ bc1,
                                                  const float* __restrict__ Wc2, const float* __restrict__ bc2,
                                                  float* __restrict__ out, int E) {
  int e = blockIdx.x * 4 + (threadIdx.x >> 6);
  int lane = threadIdx.x & 63;
  if (e >= E) return;
  int s = ei[e], t = ei[E + e];
  float h = fmaxf(ABt[(size_t)s * 64 + lane] + ABb[(size_t)t * 64 + lane] + bc1[lane], 0.0f);
  float r = wsum(h * Wc2[lane]);
  if (lane == 0) out[e] = r + bc2[0];
}

// ============================================================================
extern "C" void kernel_launch(void* const* d_in, const int* in_sizes, int n_in,
                              void* d_out, int out_size, void* d_ws, size_t ws_size,
                              hipStream_t stream) {
  const float* x = (const float*)d_in[0];
  const float* edge_attr = (const float*)d_in[1];
  const int* ei = (const int*)d_in[2];
  const int* zk = (const int*)d_in[3];
  const float* z_table = (const float*)d_in[4];
  const float* W_node = (const float*)d_in[5];
  const float* b_node = (const float*)d_in[6];
  const float* W_edge = (const float*)d_in[7];
  const float* b_edge = (const float*)d_in[8];
  const float* cn_w1 = (const float*)d_in[9];
  const float* cn_b1 = (const float*)d_in[10];
  const float* cn_w2 = (const float*)d_in[11];
  const float* cn_b2 = (const float*)d_in[12];
  const float* cn_cw1 = (const float*)d_in[13];
  const float* cn_cb1 = (const float*)d_in[14];
  const float* cn_cw2 = (const float*)d_in[15];
  const float* cn_cb2 = (const float*)d_in[16];
  const float* ce_w1 = (const float*)d_in[17];
  const float* ce_b1 = (const float*)d_in[18];
  const float* ce_w2 = (const float*)d_in[19];
  const float* ce_b2 = (const float*)d_in[20];
  const float* ce_cw1 = (const float*)d_in[21];
  const float* ce_cb1 = (const float*)d_in[22];
  const float* ce_cw2 = (const float*)d_in[23];
  const float* ce_cb2 = (const float*)d_in[24];
  const float* ln_comb_g = (const float*)d_in[25];
  const float* ln_comb_b = (const float*)d_in[26];
  const float* Wq = (const float*)d_in[27];
  const float* bq = (const float*)d_in[28];
  const float* Wk = (const float*)d_in[29];
  const float* bk = (const float*)d_in[30];
  const float* Wv = (const float*)d_in[31];
  const float* bv = (const float*)d_in[32];
  const float* Wskip = (const float*)d_in[33];
  const float* bskip = (const float*)d_in[34];
  const float* ln_tc_g = (const float*)d_in[35];
  const float* ln_tc_b = (const float*)d_in[36];
  const float* Wpn = (const float*)d_in[37];
  const float* bpn = (const float*)d_in[38];
  const float* Wpe = (const float*)d_in[39];
  const float* bpe = (const float*)d_in[40];
  const float* Wg = (const float*)d_in[41];
  const float* bg = (const float*)d_in[42];
  const float* Wc1 = (const float*)d_in[43];
  const float* bc1 = (const float*)d_in[44];
  const float* Wc2 = (const float*)d_in[45];
  const float* bc2 = (const float*)d_in[46];
  float* out = (float*)d_out;

  const int N = in_sizes[0] / 6;   // 50000
  const int E = in_sizes[2] / 2;   // 100000
  const int E2 = 2 * E;

  // ---- workspace carve (~216 MB peak) ----
  char* p = (char*)d_ws;
  auto carve = [&](size_t bytes) -> void* {
    void* r = (void*)p;
    p += (bytes + 255) & ~(size_t)255;
    return r;
  };
  unsigned short* qo = (unsigned short*)carve((size_t)N * 256 * 2);
  unsigned short* skipb = (unsigned short*)carve((size_t)N * 256 * 2); // skip -> Pe[N,128] alias
  unsigned short* kvb = (unsigned short*)carve((size_t)N * 512 * 2);
  unsigned short* aob = (unsigned short*)carve((size_t)N * 256 * 2);   // attn out -> AB f32
  unsigned short* efb = (unsigned short*)carve((size_t)E2 * 64 * 2);
  unsigned short* efc = (unsigned short*)carve((size_t)E2 * 64 * 2);
  float* nf = (float*)carve((size_t)N * 64 * 4);
  unsigned short* comb = (unsigned short*)carve((size_t)N * 128 * 2);
  unsigned short* W1t = (unsigned short*)carve((size_t)3 * 1024 * 128 * 2);
  float* bias1 = (float*)carve((size_t)3 * 1024 * 4);
  unsigned short* B2t = (unsigned short*)carve((size_t)3 * 256 * 256 * 2);
  float* bias2 = (float*)carve((size_t)3 * 256 * 4);
  unsigned short* Wg1t = (unsigned short*)carve((size_t)3 * 64 * 64 * 2);
  unsigned short* Wc1t = (unsigned short*)carve((size_t)2 * 64 * 64 * 2);
  int* cnt = (int*)carve((size_t)N * 4);
  int* cur = (int*)carve((size_t)N * 4);
  int* off = (int*)carve((size_t)(N + 1) * 4);
  int* pinv = (int*)carve((size_t)E2 * 4);
  int* slist = (int*)carve((size_t)E2 * 4);
  int* bsum = (int*)carve((size_t)256 * 4);
  int* boff = (int*)carve((size_t)256 * 4);
  float* pm = (float*)carve((size_t)PBLK * 64 * 4);
  float* ps = (float*)carve((size_t)PBLK * 64 * 4);
  float* cwv = (float*)carve(64 * 4);
  float* spmax = (float*)carve((size_t)E2 * 4);
  float* spmean = (float*)carve((size_t)E2 * 4);
  float* sconv = (float*)carve((size_t)E2 * 4);
  size_t need = (size_t)(p - (char*)d_ws);

  unsigned short* Pe = skipb;       // Pe [N,128] bf16 aliases skipb (dead after k_attn)
  float* ABt = (float*)aob;
  float* ABb = (float*)aob + (size_t)N * 64;

  auto cdiv = [](int a, int b) { return (a + b - 1) / b; };

  if (ws_size < need) {
    k_sentinel<<<cdiv(E, 256), 256, 0, stream>>>(out, E);
    return;
  }

  // ---- CSR by dst (multi-block scan) ----
  k_zero2<<<cdiv(N, 256), 256, 0, stream>>>(cnt, cur, N);
  k_hist<<<cdiv(E2, 256), 256, 0, stream>>>(ei, cnt, E);
  const int nblk = cdiv(N, 1024);
  k_scan1<<<nblk, 256, 0, stream>>>(cnt, off, bsum, N);
  k_scan2<<<1, 64, 0, stream>>>(bsum, boff, off, N, nblk);
  k_scan3<<<cdiv(N, 256), 256, 0, stream>>>(off, boff, N);
  k_scatter<<<cdiv(E2, 256), 256, 0, stream>>>(ei, off, cur, pinv, slist, E);

  // ---- pack weights (bf16 transposed) ----
  const int PACK = 3 * 1024 * 128 + 3 * 1024 + 3 * 256 * 256 + 3 * 256 + 3 * 64 * 64 + 2 * 64 * 64;
  k_packW<<<cdiv(PACK, 256), 256, 0, stream>>>(Wq, Wk, Wv, Wskip, bq, bk, bv, bskip,
                                               Wpn, Wpe, bpn, bpe, Wg, Wc1,
                                               W1t, bias1, B2t, bias2, Wg1t, Wc1t);

  // ---- embeddings ----
  k_node_embed<<<cdiv(N, 4), 256, 0, stream>>>(x, zk, z_table, W_node, b_node, nf, N);
  k_edge_embed<<<cdiv(E2, 4), 256, 0, stream>>>(x, edge_attr, ei, W_edge, b_edge, efb, E);

  // ---- CBAM: nodes (fp32, in place) then edges (bf16, scatter to CSR) ----
  k_pool_partial<float><<<PBLK, 256, 0, stream>>>(nf, N, pm, ps);
  k_pool_final<<<1, 256, 0, stream>>>(pm, ps, N, PBLK, cn_w1, cn_b1, cn_w2, cn_b2, cwv);
  k_chan_sp<float><<<cdiv(N, 16), 256, 0, stream>>>(nf, N, cwv, spmax, spmean);
  k_conv<<<cdiv(N, 256), 256, 0, stream>>>(spmax, spmean, N, cn_cw1, cn_cb1, cn_cw2, cn_cb2, sconv);
  k_row_scale<<<cdiv(N * 16, 256), 256, 0, stream>>>(nf, N, sconv);

  k_pool_partial<unsigned short><<<PBLK, 256, 0, stream>>>(efb, E2, pm, ps);
  k_pool_final<<<1, 256, 0, stream>>>(pm, ps, E2, PBLK, ce_w1, ce_b1, ce_w2, ce_b2, cwv);
  k_chan_sp<unsigned short><<<cdiv(E2, 16), 256, 0, stream>>>(efb, E2, cwv, spmax, spmean);
  k_conv<<<cdiv(E2, 256), 256, 0, stream>>>(spmax, spmean, E2, ce_cw1, ce_cb1, ce_cw2, ce_cb2, sconv);
  k_row_scale_perm<<<cdiv(E2 * 16, 256), 256, 0, stream>>>(efb, E2, sconv, pinv, efc);

  // ---- T = 3 message-passing iterations ----
  const int gqkvs = cdiv(N, 128) * 8;  // 1D, XCD-swizzled in-kernel
  dim3 gpf(cdiv(N, 128), 2);
  for (int i = 0; i < 3; ++i) {
    k_aggcomb<<<cdiv(N, 4), 256, 0, stream>>>(efc, nf, off, comb,
                                              ln_comb_g + (size_t)i * 128, ln_comb_b + (size_t)i * 128, N);
    gemm_mfma<<<gqkvs, 256, 0, stream>>>(comb, N, 128, W1t + (size_t)i * 131072,
                                         bias1 + (size_t)i * 1024, qo, kvb, skipb);
    k_attn<<<cdiv(N, 4), 256, 0, stream>>>(qo, kvb, skipb, off, slist, aob,
                                           ln_tc_g + (size_t)i * 256, ln_tc_b + (size_t)i * 256, N);
    gemm_p<<<gpf, 256, 0, stream>>>(aob, nf, N, B2t + (size_t)i * 65536,
                                    bias2 + (size_t)i * 256, Wg1t + (size_t)i * 4096,
                                    bg + (size_t)i * 64, Pe);
    gemm_gate<2><<<cdiv(E2, 128), 256, 0, stream>>>(efc, E2, Wg1t + (size_t)i * 4096, Pe,
                                                    bg + (size_t)i * 64, slist, efc);
  }

  // ---- classifier ----
  gemm_gate<0><<<cdiv(N, 128), 256, 0, stream>>>(nf, N, Wc1t, nullptr, nullptr, nullptr, ABt);
  gemm_gate<0><<<cdiv(N, 128), 256, 0, stream>>>(nf, N, Wc1t + 4096, nullptr, nullptr, nullptr, ABb);
  k_clf_pair<<<cdiv(E, 4), 256, 0, stream>>>(ABt, ABb, ei, bc1, Wc2, bc2, out, E);
  (void)out_size;
  (void)n_in;
}